// Round 1
// baseline (3727.309 us; speedup 1.0000x reference)
//
#include <hip/hip_runtime.h>

// RGCN: N=50000 nodes, E=600000 edges, D=128, R=200 rel, NB=4 bases, ARD=32, L=2, G=50, NS=2000
// Strategy:
//   per layer l:
//     k_bigw     : assemble BigW (128 x 896) = [W_b (4x128) | A_srcT (128) | A_tgtT (128) | self_loop (128)]
//     k_nodegemm : Y = X @ BigW  -> xw (N x 512), pst (N x 256 = psrc|ptgt), acc (N x 128 = curr, scatter init)
//     k_edge     : fused per-64-edge tile: q = ecat @ AcatT (reg-tiled GEMM), h=relu(psrc+ptgt+q+Ab),
//                  a=sigmoid(h·Bw+Bb), msg=Σ_b coef_b·xw[src,b], atomicAdd a·msg -> acc[tgt]
//     k_relu_pack: feats[:, l*128:+128] = relu(acc)
//   readout: gather source/target embeds; hierarchical (LDS-partial) graph mean.
// All fp32 (no fp32 MFMA on CDNA4; vector roofline 157 TF). ws usage ~231 MB.

#define NN 50000
#define EE 600000
#define DD 128
#define RR 200
#define NBASIS 4
#define LL 2
#define GG 50
#define NSRC 2000

__device__ __forceinline__ void f4a(const float4 v, float* a) {
  a[0] = v.x; a[1] = v.y; a[2] = v.z; a[3] = v.w;
}

// ---------------- BigW assembly: bigW[i*896 + c] ----------------
__global__ __launch_bounds__(256) void k_bigw(const float* __restrict__ weights,
                                              const float* __restrict__ A_w,
                                              const float* __restrict__ self_loops,
                                              float* __restrict__ bigW, int l) {
  int id = blockIdx.x * 256 + threadIdx.x;
  if (id >= 128 * 896) return;
  int i = id / 896, c = id % 896;
  float v;
  if (c < 512) {            // xw: col b*128+o  = weights[l][b][i][o]
    int b = c >> 7, o = c & 127;
    v = weights[((l * NBASIS + b) * DD + i) * DD + o];
  } else if (c < 640) {     // psrc: col 512+j = A_w[l][j][i]
    int j = c - 512;
    v = A_w[(l * DD + j) * 320 + i];
  } else if (c < 768) {     // ptgt: col 640+j = A_w[l][j][128+i]
    int j = c - 640;
    v = A_w[(l * DD + j) * 320 + 128 + i];
  } else {                  // curr: col 768+o = self_loops[l][i][o]
    int o = c - 768;
    v = self_loops[(l * DD + i) * DD + o];
  }
  bigW[id] = v;
}

// ---------------- Node GEMM: 64 nodes x 128 cols per block, K=128 ----------------
__global__ __launch_bounds__(256) void k_nodegemm(const float* __restrict__ X, int xs,
                                                  const float* __restrict__ bigW,
                                                  float* __restrict__ xw,
                                                  float* __restrict__ pst,
                                                  float* __restrict__ acc) {
  __shared__ __align__(16) float sX[64 * 68];   // [k][n] pad 68
  __shared__ __align__(16) float sW[64 * 132];  // [k][c] pad 132
  const int t = threadIdx.x;
  const int tx = t & 15, ty = t >> 4;
  const int n0 = blockIdx.x * 64;
  const int cb = blockIdx.y;  // 0..6
  float c0[4][4] = {{0}}, c1[4][4] = {{0}};
  for (int kc = 0; kc < 128; kc += 64) {
#pragma unroll
    for (int r = 0; r < 16; ++r) {  // X tile transpose-stage
      int flat = r * 256 + t;
      int nl = flat >> 6, k = flat & 63;
      int n = n0 + nl;
      sX[k * 68 + nl] = (n < NN) ? X[n * xs + kc + k] : 0.0f;
    }
#pragma unroll
    for (int r = 0; r < 32; ++r) {  // W tile
      int flat = r * 256 + t;
      int k = flat >> 7, c = flat & 127;
      sW[k * 132 + c] = bigW[(kc + k) * 896 + cb * 128 + c];
    }
    __syncthreads();
#pragma unroll 8
    for (int k = 0; k < 64; ++k) {
      float xa[4], wa[4], wb[4];
      f4a(*(const float4*)&sX[k * 68 + ty * 4], xa);
      f4a(*(const float4*)&sW[k * 132 + tx * 4], wa);
      f4a(*(const float4*)&sW[k * 132 + 64 + tx * 4], wb);
#pragma unroll
      for (int i2 = 0; i2 < 4; ++i2)
#pragma unroll
        for (int j2 = 0; j2 < 4; ++j2) {
          c0[i2][j2] += xa[i2] * wa[j2];
          c1[i2][j2] += xa[i2] * wb[j2];
        }
    }
    __syncthreads();
  }
  float* dst; int stride, off;
  if (cb < 4)       { dst = xw;  stride = 512; off = cb * 128; }
  else if (cb == 4) { dst = pst; stride = 256; off = 0; }
  else if (cb == 5) { dst = pst; stride = 256; off = 128; }
  else              { dst = acc; stride = 128; off = 0; }
#pragma unroll
  for (int i2 = 0; i2 < 4; ++i2) {
    int n = n0 + ty * 4 + i2;
    if (n >= NN) continue;
    float4 v0 = make_float4(c0[i2][0], c0[i2][1], c0[i2][2], c0[i2][3]);
    float4 v1 = make_float4(c1[i2][0], c1[i2][1], c1[i2][2], c1[i2][3]);
    *(float4*)&dst[n * stride + off + tx * 4] = v0;
    *(float4*)&dst[n * stride + off + 64 + tx * 4] = v1;
  }
}

// ---------------- Fused edge kernel: 64 edges per block ----------------
__global__ __launch_bounds__(256) void k_edge(
    const int* __restrict__ e_src, const int* __restrict__ e_tgt,
    const int* __restrict__ e_rel,
    const float* __restrict__ re, const float* __restrict__ tr,
    const float* __restrict__ w_comps, const float* __restrict__ A_w,
    const float* __restrict__ A_b, const float* __restrict__ B_w,
    const float* __restrict__ B_b,
    const float* __restrict__ xw, const float* __restrict__ pst,
    float* __restrict__ acc, int l) {
  __shared__ __align__(16) float sA[64 * 132];   // Acat[k][j] = A_w[l][j][256+k], pad 132
  __shared__ __align__(16) float sEt[64 * 68];   // ecat[k][e], pad 68
  __shared__ __align__(16) float sCf[256];       // coef[e][b]
  __shared__ float sBw[128], sAb[128];
  __shared__ int sSrc[64], sTgt[64];
  const int t = threadIdx.x;
  const int tx = t & 15, ty = t >> 4;
  const int e0 = blockIdx.x * 64;
#pragma unroll
  for (int r = 0; r < 32; ++r) {  // Acat stage (coalesced 64-float rows)
    int flat = r * 256 + t;
    int j = flat >> 6, k = flat & 63;
    sA[k * 132 + j] = A_w[(l * DD + j) * 320 + 256 + k];
  }
#pragma unroll
  for (int r = 0; r < 16; ++r) {  // ecat stage + transpose
    int flat = r * 256 + t;
    int e = flat >> 6, k = flat & 63;
    int eg = e0 + e;
    sEt[k * 68 + e] = (k < 32) ? re[eg * 32 + k] : tr[eg * 32 + (k - 32)];
  }
  if (t < 64) {
    sSrc[t] = e_src[e0 + t];
    sTgt[t] = e_tgt[e0 + t];
    int rr = e_rel[e0 + t];
    *(float4*)&sCf[t * 4] = *(const float4*)&w_comps[(l * RR + rr) * 4];
  }
  if (t < 128) { sBw[t] = B_w[l * DD + t]; sAb[t] = A_b[l * DD + t]; }
  __syncthreads();
  const float Bb = B_b[l];

  // q-GEMM: thread owns 4 edges (ty) x 8 j (tx*4, 64+tx*4)
  float q0[4][4] = {{0}}, q1[4][4] = {{0}};
#pragma unroll 8
  for (int k = 0; k < 64; ++k) {
    float ea[4], aa[4], ab[4];
    f4a(*(const float4*)&sEt[k * 68 + ty * 4], ea);
    f4a(*(const float4*)&sA[k * 132 + tx * 4], aa);
    f4a(*(const float4*)&sA[k * 132 + 64 + tx * 4], ab);
#pragma unroll
    for (int i2 = 0; i2 < 4; ++i2)
#pragma unroll
      for (int j2 = 0; j2 < 4; ++j2) {
        q0[i2][j2] += ea[i2] * aa[j2];
        q1[i2][j2] += ea[i2] * ab[j2];
      }
  }

  // per-edge epilogue
#pragma unroll
  for (int i2 = 0; i2 < 4; ++i2) {
    const int el = ty * 4 + i2;
    const int src = sSrc[el], tgt = sTgt[el];
    float ps0[4], ps1[4], pt0[4], pt1[4];
    f4a(*(const float4*)&pst[src * 256 + tx * 4], ps0);
    f4a(*(const float4*)&pst[src * 256 + 64 + tx * 4], ps1);
    f4a(*(const float4*)&pst[tgt * 256 + 128 + tx * 4], pt0);
    f4a(*(const float4*)&pst[tgt * 256 + 192 + tx * 4], pt1);
    float part = 0.0f;
    float h0[4], h1[4];
#pragma unroll
    for (int j2 = 0; j2 < 4; ++j2) {
      h0[j2] = fmaxf(ps0[j2] + pt0[j2] + q0[i2][j2] + sAb[tx * 4 + j2], 0.0f);
      h1[j2] = fmaxf(ps1[j2] + pt1[j2] + q1[i2][j2] + sAb[64 + tx * 4 + j2], 0.0f);
      part += h0[j2] * sBw[tx * 4 + j2] + h1[j2] * sBw[64 + tx * 4 + j2];
    }
#pragma unroll
    for (int m = 1; m < 16; m <<= 1) part += __shfl_xor(part, m, 64);
    const float a = 1.0f / (1.0f + expf(-(part + Bb)));
    float m0[4] = {0, 0, 0, 0}, m1[4] = {0, 0, 0, 0};
    float cf[4];
    f4a(*(const float4*)&sCf[el * 4], cf);
#pragma unroll
    for (int b = 0; b < 4; ++b) {
      float x0[4], x1[4];
      f4a(*(const float4*)&xw[src * 512 + b * 128 + tx * 4], x0);
      f4a(*(const float4*)&xw[src * 512 + b * 128 + 64 + tx * 4], x1);
#pragma unroll
      for (int j2 = 0; j2 < 4; ++j2) { m0[j2] += cf[b] * x0[j2]; m1[j2] += cf[b] * x1[j2]; }
    }
#pragma unroll
    for (int j2 = 0; j2 < 4; ++j2) {
      atomicAdd(&acc[tgt * 128 + tx * 4 + j2], a * m0[j2]);
      atomicAdd(&acc[tgt * 128 + 64 + tx * 4 + j2], a * m1[j2]);
    }
  }
}

// ---------------- relu + pack into feats ----------------
__global__ __launch_bounds__(256) void k_relu_pack(const float* __restrict__ acc,
                                                   float* __restrict__ feats, int l) {
  int id = blockIdx.x * 256 + threadIdx.x;
  if (id >= NN * DD) return;
  int n = id >> 7, d = id & 127;
  feats[n * 256 + l * 128 + d] = fmaxf(acc[id], 0.0f);
}

// ---------------- readout ----------------
__global__ __launch_bounds__(256) void k_gather(const int* __restrict__ srcn,
                                                const int* __restrict__ tgtn,
                                                const float* __restrict__ feats,
                                                float* __restrict__ out) {
  int id = blockIdx.x * 256 + threadIdx.x;
  if (id >= 2 * NSRC * 256) return;
  int half = id / (NSRC * 256);
  int rem = id % (NSRC * 256);
  int s = rem >> 8, c = rem & 255;
  int n = half ? tgtn[s] : srcn[s];
  int base = GG * 256 + half * NSRC * 256;
  out[base + s * 256 + c] = feats[n * 256 + c];
}

__global__ __launch_bounds__(256) void k_zero(float* __restrict__ p, int n) {
  int id = blockIdx.x * 256 + threadIdx.x;
  if (id < n) p[id] = 0.0f;
}

__global__ __launch_bounds__(256) void k_graphsum(const int* __restrict__ gid,
                                                  const float* __restrict__ feats,
                                                  float* __restrict__ gsum,
                                                  float* __restrict__ gcnt) {
  __shared__ float lacc[GG * 256];
  __shared__ float lcnt[GG];
  const int t = threadIdx.x;
  for (int i = t; i < GG * 256; i += 256) lacc[i] = 0.0f;
  if (t < GG) lcnt[t] = 0.0f;
  __syncthreads();
  const int base = blockIdx.x * 2000;  // 25 blocks x 2000 nodes
  for (int it = 0; it < 2000; ++it) {
    int n = base + it;
    int g = gid[n];
    lacc[g * 256 + t] += feats[n * 256 + t];
    if (t == 0) lcnt[g] += 1.0f;
  }
  __syncthreads();
  for (int i = t; i < GG * 256; i += 256) atomicAdd(&gsum[i], lacc[i]);
  if (t < GG) atomicAdd(&gcnt[t], lcnt[t]);
}

__global__ __launch_bounds__(256) void k_graphdiv(const float* __restrict__ gsum,
                                                  const float* __restrict__ gcnt,
                                                  float* __restrict__ out) {
  int id = blockIdx.x * 256 + threadIdx.x;
  if (id >= GG * 256) return;
  out[id] = gsum[id] / gcnt[id >> 8];
}

extern "C" void kernel_launch(void* const* d_in, const int* in_sizes, int n_in,
                              void* d_out, int out_size, void* d_ws, size_t ws_size,
                              hipStream_t stream) {
  const float* node_feat  = (const float*)d_in[0];
  const int*   edge       = (const int*)d_in[1];
  const int*   rel        = (const int*)d_in[2];
  const float* re         = (const float*)d_in[3];
  const float* tr         = (const float*)d_in[4];
  const int*   srcn       = (const int*)d_in[5];
  const int*   tgtn       = (const int*)d_in[6];
  const int*   gid        = (const int*)d_in[7];
  const float* weights    = (const float*)d_in[8];
  const float* w_comps    = (const float*)d_in[9];
  const float* self_loops = (const float*)d_in[10];
  const float* A_w        = (const float*)d_in[11];
  const float* A_b        = (const float*)d_in[12];
  const float* B_w        = (const float*)d_in[13];
  const float* B_b        = (const float*)d_in[14];
  float* out = (float*)d_out;

  float* ws    = (float*)d_ws;
  float* xw    = ws;                          // N*512
  float* pst   = xw + (size_t)NN * 512;       // N*256
  float* acc   = pst + (size_t)NN * 256;      // N*128
  float* feats = acc + (size_t)NN * 128;      // N*256
  float* bigW  = feats + (size_t)NN * 256;    // 128*896
  float* gsum  = bigW + 128 * 896;            // GG*256
  float* gcnt  = gsum + GG * 256;             // 64
  // total ws: ~230.9 MB

  const int* e_src = edge;
  const int* e_tgt = edge + EE;

  for (int l = 0; l < LL; ++l) {
    const float* X = (l == 0) ? node_feat : feats;  // layer1 input = feats[:, 0:128]
    int xs = (l == 0) ? 128 : 256;
    k_bigw<<<(128 * 896 + 255) / 256, 256, 0, stream>>>(weights, A_w, self_loops, bigW, l);
    dim3 g1((NN + 63) / 64, 7);
    k_nodegemm<<<g1, 256, 0, stream>>>(X, xs, bigW, xw, pst, acc);
    k_edge<<<EE / 64, 256, 0, stream>>>(e_src, e_tgt, rel, re, tr, w_comps, A_w, A_b,
                                        B_w, B_b, xw, pst, acc, l);
    k_relu_pack<<<(NN * DD + 255) / 256, 256, 0, stream>>>(acc, feats, l);
  }
  k_gather<<<(2 * NSRC * 256 + 255) / 256, 256, 0, stream>>>(srcn, tgtn, feats, out);
  k_zero<<<(GG * 256 + 64 + 255) / 256, 256, 0, stream>>>(gsum, GG * 256 + 64);
  k_graphsum<<<25, 256, 0, stream>>>(gid, feats, gsum, gcnt);
  k_graphdiv<<<GG, 256, 0, stream>>>(gsum, gcnt, out);
}

// Round 2
// 1668.761 us; speedup vs baseline: 2.2336x; 2.2336x over previous
//
#include <hip/hip_runtime.h>

// RGCN: N=50000, E=600000, D=128, R=200, NB=4, ARD=32, L=2, G=50, NS=2000
// R1 structure:
//   CSR-by-tgt built once per call (tgt is layer-invariant): hist -> 1-block scan -> fill.
//   per layer l:
//     k_bigw     : BigW (128 x 896) = [W_b(4x128) | A_srcT | A_tgtT | self_loop]
//     k_nodegemm : X @ BigW -> xw (N x 512), pst (N x 256), curr -> feats[:, l*128:+128]
//     k_attn     : fused per-64-edge q-GEMM + attention MLP -> a_e (E floats) ONLY
//     k_reduce   : wave-per-tgt-node CSR reduction: sum_e a_e * (sum_b cf_b xw[src,b]),
//                  + curr, relu, write feats in place. No atomics, no LDS.
//   readout: gather; graph mean via (graph x chunk) blocks w/ binary-searched
//            boundaries (gid monotone: gid = (i*G)//N).
// All fp32 (no fp32-input MFMA on CDNA4). ws ~211 MB.

#define NN 50000
#define EE 600000
#define DD 128
#define RR 200
#define NBASIS 4
#define LL 2
#define GG 50
#define NSRC 2000
#define GCH 8

__device__ __forceinline__ void f4a(const float4 v, float* a) {
  a[0] = v.x; a[1] = v.y; a[2] = v.z; a[3] = v.w;
}

// ---------------- BigW assembly: bigW[i*896 + c] ----------------
__global__ __launch_bounds__(256) void k_bigw(const float* __restrict__ weights,
                                              const float* __restrict__ A_w,
                                              const float* __restrict__ self_loops,
                                              float* __restrict__ bigW, int l) {
  int id = blockIdx.x * 256 + threadIdx.x;
  if (id >= 128 * 896) return;
  int i = id / 896, c = id % 896;
  float v;
  if (c < 512) {            // xw: col b*128+o = weights[l][b][i][o]
    int b = c >> 7, o = c & 127;
    v = weights[((l * NBASIS + b) * DD + i) * DD + o];
  } else if (c < 640) {     // psrc: col 512+j = A_w[l][j][i]
    int j = c - 512;
    v = A_w[(l * DD + j) * 320 + i];
  } else if (c < 768) {     // ptgt: col 640+j = A_w[l][j][128+i]
    int j = c - 640;
    v = A_w[(l * DD + j) * 320 + 128 + i];
  } else {                  // curr: col 768+o = self_loops[l][i][o]
    int o = c - 768;
    v = self_loops[(l * DD + i) * DD + o];
  }
  bigW[id] = v;
}

// ---------------- Node GEMM: 64 nodes x 128 cols per block, K=128 ----------------
__global__ __launch_bounds__(256) void k_nodegemm(const float* __restrict__ X, int xs,
                                                  const float* __restrict__ bigW,
                                                  float* __restrict__ xw,
                                                  float* __restrict__ pst,
                                                  float* __restrict__ currdst) {
  __shared__ __align__(16) float sX[64 * 68];   // [k][n] pad 68
  __shared__ __align__(16) float sW[64 * 132];  // [k][c] pad 132
  const int t = threadIdx.x;
  const int tx = t & 15, ty = t >> 4;
  const int n0 = blockIdx.x * 64;
  const int cb = blockIdx.y;  // 0..6
  float c0[4][4] = {{0}}, c1[4][4] = {{0}};
  for (int kc = 0; kc < 128; kc += 64) {
#pragma unroll
    for (int r = 0; r < 16; ++r) {  // X tile transpose-stage
      int flat = r * 256 + t;
      int nl = flat >> 6, k = flat & 63;
      int n = n0 + nl;
      sX[k * 68 + nl] = (n < NN) ? X[n * xs + kc + k] : 0.0f;
    }
#pragma unroll
    for (int r = 0; r < 32; ++r) {  // W tile
      int flat = r * 256 + t;
      int k = flat >> 7, c = flat & 127;
      sW[k * 132 + c] = bigW[(kc + k) * 896 + cb * 128 + c];
    }
    __syncthreads();
#pragma unroll 8
    for (int k = 0; k < 64; ++k) {
      float xa[4], wa[4], wb[4];
      f4a(*(const float4*)&sX[k * 68 + ty * 4], xa);
      f4a(*(const float4*)&sW[k * 132 + tx * 4], wa);
      f4a(*(const float4*)&sW[k * 132 + 64 + tx * 4], wb);
#pragma unroll
      for (int i2 = 0; i2 < 4; ++i2)
#pragma unroll
        for (int j2 = 0; j2 < 4; ++j2) {
          c0[i2][j2] += xa[i2] * wa[j2];
          c1[i2][j2] += xa[i2] * wb[j2];
        }
    }
    __syncthreads();
  }
  float* dst; int stride, off;
  if (cb < 4)       { dst = xw;      stride = 512; off = cb * 128; }
  else if (cb == 4) { dst = pst;     stride = 256; off = 0; }
  else if (cb == 5) { dst = pst;     stride = 256; off = 128; }
  else              { dst = currdst; stride = 256; off = 0; }  // feats + l*128
#pragma unroll
  for (int i2 = 0; i2 < 4; ++i2) {
    int n = n0 + ty * 4 + i2;
    if (n >= NN) continue;
    float4 v0 = make_float4(c0[i2][0], c0[i2][1], c0[i2][2], c0[i2][3]);
    float4 v1 = make_float4(c1[i2][0], c1[i2][1], c1[i2][2], c1[i2][3]);
    *(float4*)&dst[n * stride + off + tx * 4] = v0;
    *(float4*)&dst[n * stride + off + 64 + tx * 4] = v1;
  }
}

// ---------------- Attention kernel: 64 edges per block, writes a_e only ----------------
__global__ __launch_bounds__(256) void k_attn(
    const int* __restrict__ e_src, const int* __restrict__ e_tgt,
    const float* __restrict__ re, const float* __restrict__ tr,
    const float* __restrict__ A_w, const float* __restrict__ A_b,
    const float* __restrict__ B_w, const float* __restrict__ B_b,
    const float* __restrict__ pst, float* __restrict__ aatt, int l) {
  __shared__ __align__(16) float sA[64 * 132];   // Acat[k][j] = A_w[l][j][256+k]
  __shared__ __align__(16) float sEt[64 * 68];   // ecat[k][e]
  __shared__ float sBw[128], sAb[128];
  __shared__ int sSrc[64], sTgt[64];
  const int t = threadIdx.x;
  const int tx = t & 15, ty = t >> 4;
  const int e0 = blockIdx.x * 64;
#pragma unroll
  for (int r = 0; r < 32; ++r) {  // Acat stage (coalesced global rows of 64)
    int flat = r * 256 + t;
    int j = flat >> 6, k = flat & 63;
    sA[k * 132 + j] = A_w[(l * DD + j) * 320 + 256 + k];
  }
#pragma unroll
  for (int r = 0; r < 16; ++r) {  // ecat stage + transpose
    int flat = r * 256 + t;
    int e = flat >> 6, k = flat & 63;
    int eg = e0 + e;
    sEt[k * 68 + e] = (k < 32) ? re[eg * 32 + k] : tr[eg * 32 + (k - 32)];
  }
  if (t < 64) { sSrc[t] = e_src[e0 + t]; sTgt[t] = e_tgt[e0 + t]; }
  if (t < 128) { sBw[t] = B_w[l * DD + t]; sAb[t] = A_b[l * DD + t]; }
  __syncthreads();
  const float Bb = B_b[l];

  // q-GEMM: thread owns 4 edges (ty) x 8 j (tx*4, 64+tx*4)
  float q0[4][4] = {{0}}, q1[4][4] = {{0}};
#pragma unroll 8
  for (int k = 0; k < 64; ++k) {
    float ea[4], aa[4], ab[4];
    f4a(*(const float4*)&sEt[k * 68 + ty * 4], ea);
    f4a(*(const float4*)&sA[k * 132 + tx * 4], aa);
    f4a(*(const float4*)&sA[k * 132 + 64 + tx * 4], ab);
#pragma unroll
    for (int i2 = 0; i2 < 4; ++i2)
#pragma unroll
      for (int j2 = 0; j2 < 4; ++j2) {
        q0[i2][j2] += ea[i2] * aa[j2];
        q1[i2][j2] += ea[i2] * ab[j2];
      }
  }

#pragma unroll
  for (int i2 = 0; i2 < 4; ++i2) {
    const int el = ty * 4 + i2;
    const int src = sSrc[el], tgt = sTgt[el];
    float ps0[4], ps1[4], pt0[4], pt1[4];
    f4a(*(const float4*)&pst[src * 256 + tx * 4], ps0);
    f4a(*(const float4*)&pst[src * 256 + 64 + tx * 4], ps1);
    f4a(*(const float4*)&pst[tgt * 256 + 128 + tx * 4], pt0);
    f4a(*(const float4*)&pst[tgt * 256 + 192 + tx * 4], pt1);
    float part = 0.0f;
#pragma unroll
    for (int j2 = 0; j2 < 4; ++j2) {
      float h0 = fmaxf(ps0[j2] + pt0[j2] + q0[i2][j2] + sAb[tx * 4 + j2], 0.0f);
      float h1 = fmaxf(ps1[j2] + pt1[j2] + q1[i2][j2] + sAb[64 + tx * 4 + j2], 0.0f);
      part += h0 * sBw[tx * 4 + j2] + h1 * sBw[64 + tx * 4 + j2];
    }
#pragma unroll
    for (int m = 1; m < 16; m <<= 1) part += __shfl_xor(part, m, 64);
    if (tx == 0) aatt[e0 + el] = 1.0f / (1.0f + expf(-(part + Bb)));
  }
}

// ---------------- CSR build ----------------
__global__ __launch_bounds__(256) void k_zero_i(int* __restrict__ p, int n) {
  int id = blockIdx.x * 256 + threadIdx.x;
  if (id < n) p[id] = 0;
}
__global__ __launch_bounds__(256) void k_hist(const int* __restrict__ e_tgt,
                                              int* __restrict__ deg) {
  int e = blockIdx.x * 256 + threadIdx.x;
  if (e < EE) atomicAdd(&deg[e_tgt[e]], 1);
}
__global__ __launch_bounds__(1024) void k_scan(const int* __restrict__ deg,
                                               int* __restrict__ rowptr,
                                               int* __restrict__ cursor) {
  __shared__ int part[1024];
  const int t = threadIdx.x;
  const int chunk = (NN + 1023) / 1024;  // 49
  int lo = t * chunk, hi = min(lo + chunk, NN);
  int s = 0;
  for (int i = lo; i < hi; ++i) s += deg[i];
  part[t] = s;
  __syncthreads();
  for (int off = 1; off < 1024; off <<= 1) {  // Hillis-Steele inclusive
    int v = (t >= off) ? part[t - off] : 0;
    __syncthreads();
    part[t] += v;
    __syncthreads();
  }
  int run = (t == 0) ? 0 : part[t - 1];
  for (int i = lo; i < hi; ++i) {
    int d = deg[i];
    rowptr[i] = run; cursor[i] = run;
    run += d;
  }
  if (t == 0) rowptr[NN] = EE;
}
__global__ __launch_bounds__(256) void k_fill(const int* __restrict__ e_tgt,
                                              int* __restrict__ cursor,
                                              int* __restrict__ eidx) {
  int e = blockIdx.x * 256 + threadIdx.x;
  if (e < EE) { int p = atomicAdd(&cursor[e_tgt[e]], 1); eidx[p] = e; }
}

// ---------------- CSR segmented reduction: one wave per tgt node ----------------
__global__ __launch_bounds__(256) void k_reduce(
    const int* __restrict__ rowptr, const int* __restrict__ eidx,
    const int* __restrict__ e_src, const int* __restrict__ rel,
    const float* __restrict__ aatt, const float* __restrict__ w_comps,
    const float* __restrict__ xw, float* __restrict__ feats, int l) {
  const int t = threadIdx.x;
  const int wave = t >> 6, lane = t & 63;
  const int n = blockIdx.x * 4 + wave;
  if (n >= NN) return;
  const int c = lane * 2;
  float* fp = &feats[n * 256 + l * 128 + c];
  float2 s = *(const float2*)fp;  // curr from nodegemm
  const int lo = rowptr[n], hi = rowptr[n + 1];
  for (int i = lo; i < hi; ++i) {
    const int e = eidx[i];
    const int src = e_src[e];
    const float a = aatt[e];
    const float4 cf = *(const float4*)&w_comps[(l * RR + rel[e]) * 4];
    const float* xb = &xw[src * 512 + c];
    float2 x0 = *(const float2*)&xb[0];
    float2 x1 = *(const float2*)&xb[128];
    float2 x2 = *(const float2*)&xb[256];
    float2 x3 = *(const float2*)&xb[384];
    float m0 = cf.x * x0.x + cf.y * x1.x + cf.z * x2.x + cf.w * x3.x;
    float m1 = cf.x * x0.y + cf.y * x1.y + cf.z * x2.y + cf.w * x3.y;
    s.x += a * m0; s.y += a * m1;
  }
  *(float2*)fp = make_float2(fmaxf(s.x, 0.f), fmaxf(s.y, 0.f));
}

// ---------------- readout ----------------
__global__ __launch_bounds__(256) void k_gather(const int* __restrict__ srcn,
                                                const int* __restrict__ tgtn,
                                                const float* __restrict__ feats,
                                                float* __restrict__ out) {
  int id = blockIdx.x * 256 + threadIdx.x;
  if (id >= 2 * NSRC * 256) return;
  int half = id / (NSRC * 256);
  int rem = id % (NSRC * 256);
  int s = rem >> 8, c = rem & 255;
  int n = half ? tgtn[s] : srcn[s];
  int base = GG * 256 + half * NSRC * 256;
  out[base + s * 256 + c] = feats[n * 256 + c];
}

__global__ __launch_bounds__(256) void k_zero(float* __restrict__ p, int n) {
  int id = blockIdx.x * 256 + threadIdx.x;
  if (id < n) p[id] = 0.0f;
}

// graph mean: block = (g, chunk); gid is monotone ((i*G)//N), binary-search bounds
__global__ __launch_bounds__(256) void k_graphsum(const int* __restrict__ gid,
                                                  const float* __restrict__ feats,
                                                  float* __restrict__ gsum,
                                                  float* __restrict__ gcnt) {
  const int g = blockIdx.x / GCH, ch = blockIdx.x % GCH;
  __shared__ int sb[2];
  if (threadIdx.x == 0) {
    int lo = 0, hi = NN;
    while (lo < hi) { int m = (lo + hi) >> 1; if (gid[m] < g) lo = m + 1; else hi = m; }
    sb[0] = lo;
    lo = 0; hi = NN;
    while (lo < hi) { int m = (lo + hi) >> 1; if (gid[m] < g + 1) lo = m + 1; else hi = m; }
    sb[1] = lo;
  }
  __syncthreads();
  const int lo = sb[0], hi = sb[1];
  if (ch == 0 && threadIdx.x == 0) gcnt[g] = (float)(hi - lo);
  const int cnt = hi - lo;
  const int per = (cnt + GCH - 1) / GCH;
  const int nlo = lo + ch * per, nhi = min(nlo + per, hi);
  float s = 0.0f;
  const int c = threadIdx.x;
  for (int n = nlo; n < nhi; ++n) s += feats[n * 256 + c];
  atomicAdd(&gsum[g * 256 + c], s);
}

__global__ __launch_bounds__(256) void k_graphdiv(const float* __restrict__ gsum,
                                                  const float* __restrict__ gcnt,
                                                  float* __restrict__ out) {
  int id = blockIdx.x * 256 + threadIdx.x;
  if (id >= GG * 256) return;
  out[id] = gsum[id] / gcnt[id >> 8];
}

extern "C" void kernel_launch(void* const* d_in, const int* in_sizes, int n_in,
                              void* d_out, int out_size, void* d_ws, size_t ws_size,
                              hipStream_t stream) {
  const float* node_feat  = (const float*)d_in[0];
  const int*   edge       = (const int*)d_in[1];
  const int*   rel        = (const int*)d_in[2];
  const float* re         = (const float*)d_in[3];
  const float* tr         = (const float*)d_in[4];
  const int*   srcn       = (const int*)d_in[5];
  const int*   tgtn       = (const int*)d_in[6];
  const int*   gid        = (const int*)d_in[7];
  const float* weights    = (const float*)d_in[8];
  const float* w_comps    = (const float*)d_in[9];
  const float* self_loops = (const float*)d_in[10];
  const float* A_w        = (const float*)d_in[11];
  const float* A_b        = (const float*)d_in[12];
  const float* B_w        = (const float*)d_in[13];
  const float* B_b        = (const float*)d_in[14];
  float* out = (float*)d_out;

  float* ws    = (float*)d_ws;
  float* xw    = ws;                          // N*512 = 25.6M
  float* pst   = xw + (size_t)NN * 512;       // N*256
  float* feats = pst + (size_t)NN * 256;      // N*256
  float* bigW  = feats + (size_t)NN * 256;    // 128*896
  float* gsum  = bigW + 128 * 896;            // GG*256
  float* gcnt  = gsum + GG * 256;             // 64
  float* aatt  = gcnt + 64;                   // E
  int*   deg    = (int*)(aatt + EE);          // N
  int*   rowptr = deg + NN;                   // N+1
  int*   cursor = rowptr + NN + 1;            // N
  int*   eidx   = cursor + NN;                // E
  // total ws ~211 MB

  const int* e_src = edge;
  const int* e_tgt = edge + EE;

  // CSR by tgt (layer-invariant)
  k_zero_i<<<(NN + 255) / 256, 256, 0, stream>>>(deg, NN);
  k_hist<<<(EE + 255) / 256, 256, 0, stream>>>(e_tgt, deg);
  k_scan<<<1, 1024, 0, stream>>>(deg, rowptr, cursor);
  k_fill<<<(EE + 255) / 256, 256, 0, stream>>>(e_tgt, cursor, eidx);

  for (int l = 0; l < LL; ++l) {
    const float* X = (l == 0) ? node_feat : feats;  // layer1 input = feats[:, 0:128]
    int xs = (l == 0) ? 128 : 256;
    k_bigw<<<(128 * 896 + 255) / 256, 256, 0, stream>>>(weights, A_w, self_loops, bigW, l);
    dim3 g1((NN + 63) / 64, 7);
    k_nodegemm<<<g1, 256, 0, stream>>>(X, xs, bigW, xw, pst, feats + l * 128);
    k_attn<<<EE / 64, 256, 0, stream>>>(e_src, e_tgt, re, tr, A_w, A_b, B_w, B_b,
                                        pst, aatt, l);
    k_reduce<<<(NN + 3) / 4, 256, 0, stream>>>(rowptr, eidx, e_src, rel, aatt,
                                               w_comps, xw, feats, l);
  }
  k_gather<<<(2 * NSRC * 256 + 255) / 256, 256, 0, stream>>>(srcn, tgtn, feats, out);
  k_zero<<<(GG * 256 + 64 + 255) / 256, 256, 0, stream>>>(gsum, GG * 256 + 64);
  k_graphsum<<<GG * GCH, 256, 0, stream>>>(gid, feats, gsum, gcnt);
  k_graphdiv<<<GG, 256, 0, stream>>>(gsum, gcnt, out);
}

// Round 3
// 1517.007 us; speedup vs baseline: 2.4570x; 1.1000x over previous
//
#include <hip/hip_runtime.h>

// RGCN: N=50000, E=600000, D=128, R=200, NB=4, ARD=32, L=2, G=50, NS=2000
// R2: node GEMM -> bf16x2 split-precision MFMA (hi*Whi + hi*Wlo + lo*Whi, ~2^-17 rel err).
//   CSR-by-tgt (layer-invariant): hist -> 1-block scan -> fill.
//   per layer l:
//     k_bigwT    : BigW^T split -> BThi/BTlo [896][128] bf16
//     k_splitX   : X -> Xhi/Xlo [NP][128] bf16 (NP=50048 padded)
//     k_mgemm    : MFMA 16x16x32_bf16, wave=16m x 128n strip, 3 passes fused
//                  -> xw (N x 512), pst (N x 256), curr -> feats[:, l*128:+128]
//     k_attn     : fused per-64-edge q-GEMM + attention MLP -> a_e only
//     k_reduce   : wave-per-tgt CSR reduction (no atomics)
//   readout: gather + binary-searched graph mean.
// aatt aliases Xhi/Xlo (disjoint lifetimes). ws ~211 MB.

#define NN 50000
#define NP 50048   // 782 * 64
#define EE 600000
#define DD 128
#define RR 200
#define NBASIS 4
#define LL 2
#define GG 50
#define NSRC 2000
#define GCH 8

typedef __attribute__((ext_vector_type(8))) short short8v;
typedef __attribute__((ext_vector_type(4))) float float4v;

__device__ __forceinline__ void f4a(const float4 v, float* a) {
  a[0] = v.x; a[1] = v.y; a[2] = v.z; a[3] = v.w;
}

__device__ __forceinline__ unsigned short f2bf(float v) {  // RN-to-nearest-even bf16
  unsigned u = __float_as_uint(v);
  unsigned r = u + 0x7FFFu + ((u >> 16) & 1u);
  return (unsigned short)(r >> 16);
}
__device__ __forceinline__ float bf2f(unsigned short h) {
  return __uint_as_float(((unsigned)h) << 16);
}

// ---------------- BigW^T assembly + bf16x2 split: BT*[c*128 + i] ----------------
__global__ __launch_bounds__(256) void k_bigwT(const float* __restrict__ weights,
                                               const float* __restrict__ A_w,
                                               const float* __restrict__ self_loops,
                                               unsigned short* __restrict__ BThi,
                                               unsigned short* __restrict__ BTlo, int l) {
  int id = blockIdx.x * 256 + threadIdx.x;
  if (id >= 128 * 896) return;
  int i = id / 896, c = id % 896;  // i = K index, c = output col
  float v;
  if (c < 512) {            // xw: col b*128+o = weights[l][b][i][o]
    int b = c >> 7, o = c & 127;
    v = weights[((l * NBASIS + b) * DD + i) * DD + o];
  } else if (c < 640) {     // psrc: col 512+j = A_w[l][j][i]
    int j = c - 512;
    v = A_w[(l * DD + j) * 320 + i];
  } else if (c < 768) {     // ptgt: col 640+j = A_w[l][j][128+i]
    int j = c - 640;
    v = A_w[(l * DD + j) * 320 + 128 + i];
  } else {                  // curr: col 768+o = self_loops[l][i][o]
    int o = c - 768;
    v = self_loops[(l * DD + i) * DD + o];
  }
  unsigned short hi = f2bf(v);
  unsigned short lo = f2bf(v - bf2f(hi));
  BThi[c * 128 + i] = hi;
  BTlo[c * 128 + i] = lo;
}

// ---------------- X bf16x2 split (padded to NP rows) ----------------
__global__ __launch_bounds__(256) void k_splitX(const float* __restrict__ X, int xs,
                                                unsigned short* __restrict__ Xhi,
                                                unsigned short* __restrict__ Xlo) {
  int id = blockIdx.x * 256 + threadIdx.x;
  if (id >= NP * 128) return;
  int n = id >> 7, k = id & 127;
  float v = (n < NN) ? X[(size_t)n * xs + k] : 0.0f;
  unsigned short hi = f2bf(v);
  unsigned short lo = f2bf(v - bf2f(hi));
  Xhi[id] = hi;
  Xlo[id] = lo;
}

// ---------------- MFMA node GEMM: block = 64m x 128n, wave = 16m x 128n ----------------
__global__ __launch_bounds__(256) void k_mgemm(const unsigned short* __restrict__ Xhi,
                                               const unsigned short* __restrict__ Xlo,
                                               const unsigned short* __restrict__ BThi,
                                               const unsigned short* __restrict__ BTlo,
                                               float* __restrict__ xw,
                                               float* __restrict__ pst,
                                               float* __restrict__ currdst) {
  const int t = threadIdx.x;
  const int wv = t >> 6, lane = t & 63;
  const int lm = lane & 15, qd = lane >> 4;
  const int m0 = blockIdx.x * 64 + wv * 16;
  const int cb = blockIdx.y;           // 0..6
  const int n0 = cb * 128;
  float4v acc[8];
#pragma unroll
  for (int i = 0; i < 8; ++i) acc[i] = (float4v)(0.0f);
  const unsigned short* xh = Xhi + (size_t)(m0 + lm) * 128 + qd * 8;
  const unsigned short* xl = Xlo + (size_t)(m0 + lm) * 128 + qd * 8;
  const unsigned short* bh = BThi + (size_t)(n0 + lm) * 128 + qd * 8;
  const unsigned short* bl = BTlo + (size_t)(n0 + lm) * 128 + qd * 8;
#pragma unroll
  for (int kc = 0; kc < 128; kc += 32) {
    short8v ah = *(const short8v*)(const void*)(xh + kc);
    short8v al = *(const short8v*)(const void*)(xl + kc);
#pragma unroll
    for (int nt = 0; nt < 8; ++nt) {
      short8v bhv = *(const short8v*)(const void*)(bh + nt * 16 * 128 + kc);
      short8v blv = *(const short8v*)(const void*)(bl + nt * 16 * 128 + kc);
      acc[nt] = __builtin_amdgcn_mfma_f32_16x16x32_bf16(ah, bhv, acc[nt], 0, 0, 0);
      acc[nt] = __builtin_amdgcn_mfma_f32_16x16x32_bf16(ah, blv, acc[nt], 0, 0, 0);
      acc[nt] = __builtin_amdgcn_mfma_f32_16x16x32_bf16(al, bhv, acc[nt], 0, 0, 0);
    }
  }
  float* dst; int stride, off;
  if (cb < 4)       { dst = xw;      stride = 512; off = cb * 128; }
  else if (cb == 4) { dst = pst;     stride = 256; off = 0; }
  else if (cb == 5) { dst = pst;     stride = 256; off = 128; }
  else              { dst = currdst; stride = 256; off = 0; }  // feats + l*128
  // C/D layout: col = lane&15, row = (lane>>4)*4 + reg  [measured m89/m91]
#pragma unroll
  for (int nt = 0; nt < 8; ++nt) {
#pragma unroll
    for (int r = 0; r < 4; ++r) {
      int m = m0 + qd * 4 + r;
      if (m < NN) dst[(size_t)m * stride + off + nt * 16 + lm] = acc[nt][r];
    }
  }
}

// ---------------- Attention kernel: 64 edges per block, writes a_e only ----------------
__global__ __launch_bounds__(256) void k_attn(
    const int* __restrict__ e_src, const int* __restrict__ e_tgt,
    const float* __restrict__ re, const float* __restrict__ tr,
    const float* __restrict__ A_w, const float* __restrict__ A_b,
    const float* __restrict__ B_w, const float* __restrict__ B_b,
    const float* __restrict__ pst, float* __restrict__ aatt, int l) {
  __shared__ __align__(16) float sA[64 * 132];   // Acat[k][j] = A_w[l][j][256+k]
  __shared__ __align__(16) float sEt[64 * 68];   // ecat[k][e]
  __shared__ float sBw[128], sAb[128];
  __shared__ int sSrc[64], sTgt[64];
  const int t = threadIdx.x;
  const int tx = t & 15, ty = t >> 4;
  const int e0 = blockIdx.x * 64;
#pragma unroll
  for (int r = 0; r < 32; ++r) {
    int flat = r * 256 + t;
    int j = flat >> 6, k = flat & 63;
    sA[k * 132 + j] = A_w[(l * DD + j) * 320 + 256 + k];
  }
#pragma unroll
  for (int r = 0; r < 16; ++r) {
    int flat = r * 256 + t;
    int e = flat >> 6, k = flat & 63;
    int eg = e0 + e;
    sEt[k * 68 + e] = (k < 32) ? re[eg * 32 + k] : tr[eg * 32 + (k - 32)];
  }
  if (t < 64) { sSrc[t] = e_src[e0 + t]; sTgt[t] = e_tgt[e0 + t]; }
  if (t < 128) { sBw[t] = B_w[l * DD + t]; sAb[t] = A_b[l * DD + t]; }
  __syncthreads();
  const float Bb = B_b[l];

  float q0[4][4] = {{0}}, q1[4][4] = {{0}};
#pragma unroll 8
  for (int k = 0; k < 64; ++k) {
    float ea[4], aa[4], ab[4];
    f4a(*(const float4*)&sEt[k * 68 + ty * 4], ea);
    f4a(*(const float4*)&sA[k * 132 + tx * 4], aa);
    f4a(*(const float4*)&sA[k * 132 + 64 + tx * 4], ab);
#pragma unroll
    for (int i2 = 0; i2 < 4; ++i2)
#pragma unroll
      for (int j2 = 0; j2 < 4; ++j2) {
        q0[i2][j2] += ea[i2] * aa[j2];
        q1[i2][j2] += ea[i2] * ab[j2];
      }
  }

#pragma unroll
  for (int i2 = 0; i2 < 4; ++i2) {
    const int el = ty * 4 + i2;
    const int src = sSrc[el], tgt = sTgt[el];
    float ps0[4], ps1[4], pt0[4], pt1[4];
    f4a(*(const float4*)&pst[src * 256 + tx * 4], ps0);
    f4a(*(const float4*)&pst[src * 256 + 64 + tx * 4], ps1);
    f4a(*(const float4*)&pst[tgt * 256 + 128 + tx * 4], pt0);
    f4a(*(const float4*)&pst[tgt * 256 + 192 + tx * 4], pt1);
    float part = 0.0f;
#pragma unroll
    for (int j2 = 0; j2 < 4; ++j2) {
      float h0 = fmaxf(ps0[j2] + pt0[j2] + q0[i2][j2] + sAb[tx * 4 + j2], 0.0f);
      float h1 = fmaxf(ps1[j2] + pt1[j2] + q1[i2][j2] + sAb[64 + tx * 4 + j2], 0.0f);
      part += h0 * sBw[tx * 4 + j2] + h1 * sBw[64 + tx * 4 + j2];
    }
#pragma unroll
    for (int m = 1; m < 16; m <<= 1) part += __shfl_xor(part, m, 64);
    if (tx == 0) aatt[e0 + el] = 1.0f / (1.0f + expf(-(part + Bb)));
  }
}

// ---------------- CSR build ----------------
__global__ __launch_bounds__(256) void k_zero_i(int* __restrict__ p, int n) {
  int id = blockIdx.x * 256 + threadIdx.x;
  if (id < n) p[id] = 0;
}
__global__ __launch_bounds__(256) void k_hist(const int* __restrict__ e_tgt,
                                              int* __restrict__ deg) {
  int e = blockIdx.x * 256 + threadIdx.x;
  if (e < EE) atomicAdd(&deg[e_tgt[e]], 1);
}
__global__ __launch_bounds__(1024) void k_scan(const int* __restrict__ deg,
                                               int* __restrict__ rowptr,
                                               int* __restrict__ cursor) {
  __shared__ int part[1024];
  const int t = threadIdx.x;
  const int chunk = (NN + 1023) / 1024;  // 49
  int lo = t * chunk, hi = min(lo + chunk, NN);
  int s = 0;
  for (int i = lo; i < hi; ++i) s += deg[i];
  part[t] = s;
  __syncthreads();
  for (int off = 1; off < 1024; off <<= 1) {
    int v = (t >= off) ? part[t - off] : 0;
    __syncthreads();
    part[t] += v;
    __syncthreads();
  }
  int run = (t == 0) ? 0 : part[t - 1];
  for (int i = lo; i < hi; ++i) {
    int d = deg[i];
    rowptr[i] = run; cursor[i] = run;
    run += d;
  }
  if (t == 0) rowptr[NN] = EE;
}
__global__ __launch_bounds__(256) void k_fill(const int* __restrict__ e_tgt,
                                              int* __restrict__ cursor,
                                              int* __restrict__ eidx) {
  int e = blockIdx.x * 256 + threadIdx.x;
  if (e < EE) { int p = atomicAdd(&cursor[e_tgt[e]], 1); eidx[p] = e; }
}

// ---------------- CSR segmented reduction: one wave per tgt node ----------------
__global__ __launch_bounds__(256) void k_reduce(
    const int* __restrict__ rowptr, const int* __restrict__ eidx,
    const int* __restrict__ e_src, const int* __restrict__ rel,
    const float* __restrict__ aatt, const float* __restrict__ w_comps,
    const float* __restrict__ xw, float* __restrict__ feats, int l) {
  const int t = threadIdx.x;
  const int wave = t >> 6, lane = t & 63;
  const int n = blockIdx.x * 4 + wave;
  if (n >= NN) return;
  const int c = lane * 2;
  float* fp = &feats[n * 256 + l * 128 + c];
  float2 s = *(const float2*)fp;  // curr from mgemm
  const int lo = rowptr[n], hi = rowptr[n + 1];
  for (int i = lo; i < hi; ++i) {
    const int e = eidx[i];
    const int src = e_src[e];
    const float a = aatt[e];
    const float4 cf = *(const float4*)&w_comps[(l * RR + rel[e]) * 4];
    const float* xb = &xw[src * 512 + c];
    float2 x0 = *(const float2*)&xb[0];
    float2 x1 = *(const float2*)&xb[128];
    float2 x2 = *(const float2*)&xb[256];
    float2 x3 = *(const float2*)&xb[384];
    float m0 = cf.x * x0.x + cf.y * x1.x + cf.z * x2.x + cf.w * x3.x;
    float m1 = cf.x * x0.y + cf.y * x1.y + cf.z * x2.y + cf.w * x3.y;
    s.x += a * m0; s.y += a * m1;
  }
  *(float2*)fp = make_float2(fmaxf(s.x, 0.f), fmaxf(s.y, 0.f));
}

// ---------------- readout ----------------
__global__ __launch_bounds__(256) void k_gather(const int* __restrict__ srcn,
                                                const int* __restrict__ tgtn,
                                                const float* __restrict__ feats,
                                                float* __restrict__ out) {
  int id = blockIdx.x * 256 + threadIdx.x;
  if (id >= 2 * NSRC * 256) return;
  int half = id / (NSRC * 256);
  int rem = id % (NSRC * 256);
  int s = rem >> 8, c = rem & 255;
  int n = half ? tgtn[s] : srcn[s];
  int base = GG * 256 + half * NSRC * 256;
  out[base + s * 256 + c] = feats[n * 256 + c];
}

__global__ __launch_bounds__(256) void k_zero(float* __restrict__ p, int n) {
  int id = blockIdx.x * 256 + threadIdx.x;
  if (id < n) p[id] = 0.0f;
}

__global__ __launch_bounds__(256) void k_graphsum(const int* __restrict__ gid,
                                                  const float* __restrict__ feats,
                                                  float* __restrict__ gsum,
                                                  float* __restrict__ gcnt) {
  const int g = blockIdx.x / GCH, ch = blockIdx.x % GCH;
  __shared__ int sb[2];
  if (threadIdx.x == 0) {
    int lo = 0, hi = NN;
    while (lo < hi) { int m = (lo + hi) >> 1; if (gid[m] < g) lo = m + 1; else hi = m; }
    sb[0] = lo;
    lo = 0; hi = NN;
    while (lo < hi) { int m = (lo + hi) >> 1; if (gid[m] < g + 1) lo = m + 1; else hi = m; }
    sb[1] = lo;
  }
  __syncthreads();
  const int lo = sb[0], hi = sb[1];
  if (ch == 0 && threadIdx.x == 0) gcnt[g] = (float)(hi - lo);
  const int cnt = hi - lo;
  const int per = (cnt + GCH - 1) / GCH;
  const int nlo = lo + ch * per, nhi = min(nlo + per, hi);
  float s = 0.0f;
  const int c = threadIdx.x;
  for (int n = nlo; n < nhi; ++n) s += feats[n * 256 + c];
  atomicAdd(&gsum[g * 256 + c], s);
}

__global__ __launch_bounds__(256) void k_graphdiv(const float* __restrict__ gsum,
                                                  const float* __restrict__ gcnt,
                                                  float* __restrict__ out) {
  int id = blockIdx.x * 256 + threadIdx.x;
  if (id >= GG * 256) return;
  out[id] = gsum[id] / gcnt[id >> 8];
}

extern "C" void kernel_launch(void* const* d_in, const int* in_sizes, int n_in,
                              void* d_out, int out_size, void* d_ws, size_t ws_size,
                              hipStream_t stream) {
  const float* node_feat  = (const float*)d_in[0];
  const int*   edge       = (const int*)d_in[1];
  const int*   rel        = (const int*)d_in[2];
  const float* re         = (const float*)d_in[3];
  const float* tr         = (const float*)d_in[4];
  const int*   srcn       = (const int*)d_in[5];
  const int*   tgtn       = (const int*)d_in[6];
  const int*   gid        = (const int*)d_in[7];
  const float* weights    = (const float*)d_in[8];
  const float* w_comps    = (const float*)d_in[9];
  const float* self_loops = (const float*)d_in[10];
  const float* A_w        = (const float*)d_in[11];
  const float* A_b        = (const float*)d_in[12];
  const float* B_w        = (const float*)d_in[13];
  const float* B_b        = (const float*)d_in[14];
  float* out = (float*)d_out;

  float* ws    = (float*)d_ws;
  float* xw    = ws;                           // N*512
  float* pst   = xw + (size_t)NN * 512;        // N*256
  float* feats = pst + (size_t)NN * 256;       // N*256
  float* gsum  = feats + (size_t)NN * 256;     // GG*256
  float* gcnt  = gsum + GG * 256;              // 64
  // split region: Xhi/Xlo [NP*128 ushort each]; aatt aliases it (disjoint lifetime)
  unsigned short* Xhi = (unsigned short*)(gcnt + 64);
  unsigned short* Xlo = Xhi + (size_t)NP * 128;
  float* aatt = (float*)Xhi;                   // E floats <= NP*128 ushorts
  unsigned short* BThi = Xlo + (size_t)NP * 128;   // 896*128
  unsigned short* BTlo = BThi + 896 * 128;
  int*   deg    = (int*)(BTlo + 896 * 128);    // N
  int*   rowptr = deg + NN;                    // N+1
  int*   cursor = rowptr + NN + 1;             // N
  int*   eidx   = cursor + NN;                 // E
  // total ws ~211 MB

  const int* e_src = edge;
  const int* e_tgt = edge + EE;

  // CSR by tgt (layer-invariant)
  k_zero_i<<<(NN + 255) / 256, 256, 0, stream>>>(deg, NN);
  k_hist<<<(EE + 255) / 256, 256, 0, stream>>>(e_tgt, deg);
  k_scan<<<1, 1024, 0, stream>>>(deg, rowptr, cursor);
  k_fill<<<(EE + 255) / 256, 256, 0, stream>>>(e_tgt, cursor, eidx);

  for (int l = 0; l < LL; ++l) {
    const float* X = (l == 0) ? node_feat : feats;  // layer1 input = feats[:, 0:128]
    int xs = (l == 0) ? 128 : 256;
    k_bigwT<<<(128 * 896 + 255) / 256, 256, 0, stream>>>(weights, A_w, self_loops,
                                                         BThi, BTlo, l);
    k_splitX<<<(NP * 128 + 255) / 256, 256, 0, stream>>>(X, xs, Xhi, Xlo);
    dim3 g1(NP / 64, 7);
    k_mgemm<<<g1, 256, 0, stream>>>(Xhi, Xlo, BThi, BTlo, xw, pst, feats + l * 128);
    k_attn<<<EE / 64, 256, 0, stream>>>(e_src, e_tgt, re, tr, A_w, A_b, B_w, B_b,
                                        pst, aatt, l);
    k_reduce<<<(NN + 3) / 4, 256, 0, stream>>>(rowptr, eidx, e_src, rel, aatt,
                                               w_comps, xw, feats, l);
  }
  k_gather<<<(2 * NSRC * 256 + 255) / 256, 256, 0, stream>>>(srcn, tgtn, feats, out);
  k_zero<<<(GG * 256 + 64 + 255) / 256, 256, 0, stream>>>(gsum, GG * 256 + 64);
  k_graphsum<<<GG * GCH, 256, 0, stream>>>(gid, feats, gsum, gcnt);
  k_graphdiv<<<GG, 256, 0, stream>>>(gsum, gcnt, out);
}

// Round 4
// 1322.085 us; speedup vs baseline: 2.8193x; 1.1474x over previous
//
#include <hip/hip_runtime.h>

// RGCN: N=50000, E=600000, D=128, R=200, NB=4, ARD=32, L=2, G=50, NS=2000
// R3: fp16 gather tables (xw16, pst16) halve the edge-gather byte streams that
//     dominate (reduce 2048->1024 B/edge, attn 1024->512 B/edge); CSR prep pass
//     (srcs, a*cf) kills the eidx->src dependent chain; reduce uses one half8
//     (16 B) load/lane/edge with shfl_xor basis reduction.
//   per layer l:
//     k_bigwT  : BigW^T split -> BThi/BTlo [896][128] bf16
//     k_splitX : X -> Xhi/Xlo bf16x2 (NP=50048 padded)
//     k_mgemm  : 3-pass bf16x2 MFMA -> xw16 (N x 512 fp16), pst16 (N x 256 fp16),
//                curr -> feats[:, l*128:+128] fp32
//     k_attn   : per-64-edge q-GEMM (VALU) + MLP, fp16 pst gathers -> aatt
//     k_prep   : srcs[i], acf[i]=a_e*cf4[rel_e] in CSR order
//     k_reduce : wave-per-tgt CSR reduction over fp16 xw, fp32 accum
// All accumulation fp32. ws ~171 MB.

#define NN 50000
#define NP 50048   // 782 * 64
#define EE 600000
#define DD 128
#define RR 200
#define NBASIS 4
#define LL 2
#define GG 50
#define NSRC 2000
#define GCH 8

typedef __attribute__((ext_vector_type(8))) short short8v;
typedef __attribute__((ext_vector_type(4))) float float4v;
typedef __attribute__((ext_vector_type(8))) _Float16 half8v;
typedef __attribute__((ext_vector_type(4))) _Float16 half4v;

__device__ __forceinline__ void f4a(const float4 v, float* a) {
  a[0] = v.x; a[1] = v.y; a[2] = v.z; a[3] = v.w;
}

__device__ __forceinline__ unsigned short f2bf(float v) {  // RNE bf16
  unsigned u = __float_as_uint(v);
  unsigned r = u + 0x7FFFu + ((u >> 16) & 1u);
  return (unsigned short)(r >> 16);
}
__device__ __forceinline__ float bf2f(unsigned short h) {
  return __uint_as_float(((unsigned)h) << 16);
}

// ---------------- BigW^T assembly + bf16x2 split: BT*[c*128 + i] ----------------
__global__ __launch_bounds__(256) void k_bigwT(const float* __restrict__ weights,
                                               const float* __restrict__ A_w,
                                               const float* __restrict__ self_loops,
                                               unsigned short* __restrict__ BThi,
                                               unsigned short* __restrict__ BTlo, int l) {
  int id = blockIdx.x * 256 + threadIdx.x;
  if (id >= 128 * 896) return;
  int i = id / 896, c = id % 896;  // i = K index, c = output col
  float v;
  if (c < 512) {            // xw: col b*128+o = weights[l][b][i][o]
    int b = c >> 7, o = c & 127;
    v = weights[((l * NBASIS + b) * DD + i) * DD + o];
  } else if (c < 640) {     // psrc: col 512+j = A_w[l][j][i]
    int j = c - 512;
    v = A_w[(l * DD + j) * 320 + i];
  } else if (c < 768) {     // ptgt: col 640+j = A_w[l][j][128+i]
    int j = c - 640;
    v = A_w[(l * DD + j) * 320 + 128 + i];
  } else {                  // curr: col 768+o = self_loops[l][i][o]
    int o = c - 768;
    v = self_loops[(l * DD + i) * DD + o];
  }
  unsigned short hi = f2bf(v);
  unsigned short lo = f2bf(v - bf2f(hi));
  BThi[c * 128 + i] = hi;
  BTlo[c * 128 + i] = lo;
}

// ---------------- X bf16x2 split (padded to NP rows) ----------------
__global__ __launch_bounds__(256) void k_splitX(const float* __restrict__ X, int xs,
                                                unsigned short* __restrict__ Xhi,
                                                unsigned short* __restrict__ Xlo) {
  int id = blockIdx.x * 256 + threadIdx.x;
  if (id >= NP * 128) return;
  int n = id >> 7, k = id & 127;
  float v = (n < NN) ? X[(size_t)n * xs + k] : 0.0f;
  unsigned short hi = f2bf(v);
  unsigned short lo = f2bf(v - bf2f(hi));
  Xhi[id] = hi;
  Xlo[id] = lo;
}

// ---------------- MFMA node GEMM: block = 64m x 128n, wave = 16m x 128n ----------------
__global__ __launch_bounds__(256) void k_mgemm(const unsigned short* __restrict__ Xhi,
                                               const unsigned short* __restrict__ Xlo,
                                               const unsigned short* __restrict__ BThi,
                                               const unsigned short* __restrict__ BTlo,
                                               _Float16* __restrict__ xw16,
                                               _Float16* __restrict__ pst16,
                                               float* __restrict__ currdst) {
  const int t = threadIdx.x;
  const int wv = t >> 6, lane = t & 63;
  const int lm = lane & 15, qd = lane >> 4;
  const int m0 = blockIdx.x * 64 + wv * 16;
  const int cb = blockIdx.y;           // 0..6
  const int n0 = cb * 128;
  float4v acc[8];
#pragma unroll
  for (int i = 0; i < 8; ++i) acc[i] = (float4v)(0.0f);
  const unsigned short* xh = Xhi + (size_t)(m0 + lm) * 128 + qd * 8;
  const unsigned short* xl = Xlo + (size_t)(m0 + lm) * 128 + qd * 8;
  const unsigned short* bh = BThi + (size_t)(n0 + lm) * 128 + qd * 8;
  const unsigned short* bl = BTlo + (size_t)(n0 + lm) * 128 + qd * 8;
#pragma unroll
  for (int kc = 0; kc < 128; kc += 32) {
    short8v ah = *(const short8v*)(const void*)(xh + kc);
    short8v al = *(const short8v*)(const void*)(xl + kc);
#pragma unroll
    for (int nt = 0; nt < 8; ++nt) {
      short8v bhv = *(const short8v*)(const void*)(bh + nt * 16 * 128 + kc);
      short8v blv = *(const short8v*)(const void*)(bl + nt * 16 * 128 + kc);
      acc[nt] = __builtin_amdgcn_mfma_f32_16x16x32_bf16(ah, bhv, acc[nt], 0, 0, 0);
      acc[nt] = __builtin_amdgcn_mfma_f32_16x16x32_bf16(ah, blv, acc[nt], 0, 0, 0);
      acc[nt] = __builtin_amdgcn_mfma_f32_16x16x32_bf16(al, bhv, acc[nt], 0, 0, 0);
    }
  }
  // C/D layout: col = lane&15, row = (lane>>4)*4 + reg  [measured m89/m91]
  if (cb < 6) {  // fp16 gather tables
    _Float16* dst16; int stride, off;
    if (cb < 4) { dst16 = xw16;  stride = 512; off = cb * 128; }
    else        { dst16 = pst16; stride = 256; off = (cb - 4) * 128; }
#pragma unroll
    for (int nt = 0; nt < 8; ++nt) {
#pragma unroll
      for (int r = 0; r < 4; ++r) {
        int m = m0 + qd * 4 + r;
        if (m < NN) dst16[(size_t)m * stride + off + nt * 16 + lm] = (_Float16)acc[nt][r];
      }
    }
  } else {       // curr -> feats fp32
#pragma unroll
    for (int nt = 0; nt < 8; ++nt) {
#pragma unroll
      for (int r = 0; r < 4; ++r) {
        int m = m0 + qd * 4 + r;
        if (m < NN) currdst[(size_t)m * 256 + nt * 16 + lm] = acc[nt][r];
      }
    }
  }
}

// ---------------- Attention kernel: 64 edges per block, writes a_e only ----------------
__global__ __launch_bounds__(256) void k_attn(
    const int* __restrict__ e_src, const int* __restrict__ e_tgt,
    const float* __restrict__ re, const float* __restrict__ tr,
    const float* __restrict__ A_w, const float* __restrict__ A_b,
    const float* __restrict__ B_w, const float* __restrict__ B_b,
    const _Float16* __restrict__ pst16, float* __restrict__ aatt, int l) {
  __shared__ __align__(16) float sA[64 * 132];   // Acat[k][j] = A_w[l][j][256+k]
  __shared__ __align__(16) float sEt[64 * 68];   // ecat[k][e]
  __shared__ float sBw[128], sAb[128];
  __shared__ int sSrc[64], sTgt[64];
  const int t = threadIdx.x;
  const int tx = t & 15, ty = t >> 4;
  const int e0 = blockIdx.x * 64;
#pragma unroll
  for (int r = 0; r < 32; ++r) {
    int flat = r * 256 + t;
    int j = flat >> 6, k = flat & 63;
    sA[k * 132 + j] = A_w[(l * DD + j) * 320 + 256 + k];
  }
#pragma unroll
  for (int r = 0; r < 16; ++r) {
    int flat = r * 256 + t;
    int e = flat >> 6, k = flat & 63;
    int eg = e0 + e;
    sEt[k * 68 + e] = (k < 32) ? re[eg * 32 + k] : tr[eg * 32 + (k - 32)];
  }
  if (t < 64) { sSrc[t] = e_src[e0 + t]; sTgt[t] = e_tgt[e0 + t]; }
  if (t < 128) { sBw[t] = B_w[l * DD + t]; sAb[t] = A_b[l * DD + t]; }
  __syncthreads();
  const float Bb = B_b[l];

  float q0[4][4] = {{0}}, q1[4][4] = {{0}};
#pragma unroll 8
  for (int k = 0; k < 64; ++k) {
    float ea[4], aa[4], ab[4];
    f4a(*(const float4*)&sEt[k * 68 + ty * 4], ea);
    f4a(*(const float4*)&sA[k * 132 + tx * 4], aa);
    f4a(*(const float4*)&sA[k * 132 + 64 + tx * 4], ab);
#pragma unroll
    for (int i2 = 0; i2 < 4; ++i2)
#pragma unroll
      for (int j2 = 0; j2 < 4; ++j2) {
        q0[i2][j2] += ea[i2] * aa[j2];
        q1[i2][j2] += ea[i2] * ab[j2];
      }
  }

#pragma unroll
  for (int i2 = 0; i2 < 4; ++i2) {
    const int el = ty * 4 + i2;
    const int src = sSrc[el], tgt = sTgt[el];
    half4v hp0 = *(const half4v*)&pst16[(size_t)src * 256 + tx * 4];
    half4v hp1 = *(const half4v*)&pst16[(size_t)src * 256 + 64 + tx * 4];
    half4v ht0 = *(const half4v*)&pst16[(size_t)tgt * 256 + 128 + tx * 4];
    half4v ht1 = *(const half4v*)&pst16[(size_t)tgt * 256 + 192 + tx * 4];
    float part = 0.0f;
#pragma unroll
    for (int j2 = 0; j2 < 4; ++j2) {
      float h0 = fmaxf((float)hp0[j2] + (float)ht0[j2] + q0[i2][j2] + sAb[tx * 4 + j2], 0.0f);
      float h1 = fmaxf((float)hp1[j2] + (float)ht1[j2] + q1[i2][j2] + sAb[64 + tx * 4 + j2], 0.0f);
      part += h0 * sBw[tx * 4 + j2] + h1 * sBw[64 + tx * 4 + j2];
    }
#pragma unroll
    for (int m = 1; m < 16; m <<= 1) part += __shfl_xor(part, m, 64);
    if (tx == 0) aatt[e0 + el] = 1.0f / (1.0f + expf(-(part + Bb)));
  }
}

// ---------------- CSR build ----------------
__global__ __launch_bounds__(256) void k_zero_i(int* __restrict__ p, int n) {
  int id = blockIdx.x * 256 + threadIdx.x;
  if (id < n) p[id] = 0;
}
__global__ __launch_bounds__(256) void k_hist(const int* __restrict__ e_tgt,
                                              int* __restrict__ deg) {
  int e = blockIdx.x * 256 + threadIdx.x;
  if (e < EE) atomicAdd(&deg[e_tgt[e]], 1);
}
__global__ __launch_bounds__(1024) void k_scan(const int* __restrict__ deg,
                                               int* __restrict__ rowptr,
                                               int* __restrict__ cursor) {
  __shared__ int part[1024];
  const int t = threadIdx.x;
  const int chunk = (NN + 1023) / 1024;  // 49
  int lo = t * chunk, hi = min(lo + chunk, NN);
  int s = 0;
  for (int i = lo; i < hi; ++i) s += deg[i];
  part[t] = s;
  __syncthreads();
  for (int off = 1; off < 1024; off <<= 1) {
    int v = (t >= off) ? part[t - off] : 0;
    __syncthreads();
    part[t] += v;
    __syncthreads();
  }
  int run = (t == 0) ? 0 : part[t - 1];
  for (int i = lo; i < hi; ++i) {
    int d = deg[i];
    rowptr[i] = run; cursor[i] = run;
    run += d;
  }
  if (t == 0) rowptr[NN] = EE;
}
__global__ __launch_bounds__(256) void k_fill(const int* __restrict__ e_tgt,
                                              int* __restrict__ cursor,
                                              int* __restrict__ eidx) {
  int e = blockIdx.x * 256 + threadIdx.x;
  if (e < EE) { int p = atomicAdd(&cursor[e_tgt[e]], 1); eidx[p] = e; }
}

// ---------------- CSR-order prep: srcs[i], acf[i] = a_e * cf4[rel_e] ----------------
__global__ __launch_bounds__(256) void k_prep(const int* __restrict__ eidx,
                                              const int* __restrict__ e_src,
                                              const int* __restrict__ rel,
                                              const float* __restrict__ aatt,
                                              const float* __restrict__ w_comps,
                                              int* __restrict__ srcs,
                                              float* __restrict__ acf, int l) {
  int i = blockIdx.x * 256 + threadIdx.x;
  if (i >= EE) return;
  int e = eidx[i];
  srcs[i] = e_src[e];
  float a = aatt[e];
  float4 cf = *(const float4*)&w_comps[(l * RR + rel[e]) * 4];
  *(float4*)&acf[i * 4] = make_float4(a * cf.x, a * cf.y, a * cf.z, a * cf.w);
}

// ---------------- CSR segmented reduction: one wave per tgt node ----------------
// lane = (b, li): b = lane>>4 basis, li = lane&15 covers cols li*8..+7 of basis b.
// One half8 (16 B) load per lane per edge -> whole wave reads the contiguous
// 1024 B xw16 row. Basis reduction via shfl_xor(16|32) at end.
__global__ __launch_bounds__(256) void k_reduce(
    const int* __restrict__ rowptr, const int* __restrict__ srcs,
    const float* __restrict__ acf, const _Float16* __restrict__ xw16,
    float* __restrict__ feats, int l) {
  const int t = threadIdx.x;
  const int wave = t >> 6, lane = t & 63;
  const int n = blockIdx.x * 4 + wave;
  if (n >= NN) return;
  const int b = lane >> 4, li = lane & 15;
  float s[8] = {0, 0, 0, 0, 0, 0, 0, 0};
  const int lo = rowptr[n], hi = rowptr[n + 1];
  int snext = 0; float cnext = 0.0f;
  if (lo < hi) { snext = srcs[lo]; cnext = acf[lo * 4 + b]; }
  for (int i = lo; i < hi; ++i) {
    const int src = snext; const float cb_ = cnext;
    if (i + 1 < hi) { snext = srcs[i + 1]; cnext = acf[(i + 1) * 4 + b]; }
    half8v x = *(const half8v*)&xw16[(size_t)src * 512 + b * 128 + li * 8];
#pragma unroll
    for (int j = 0; j < 8; ++j) s[j] += cb_ * (float)x[j];
  }
#pragma unroll
  for (int j = 0; j < 8; ++j) {
    s[j] += __shfl_xor(s[j], 16, 64);
    s[j] += __shfl_xor(s[j], 32, 64);
  }
  if (lane < 16) {
    float* fp = &feats[(size_t)n * 256 + l * 128 + lane * 8];
    float4 c0 = *(const float4*)fp;
    float4 c1 = *(const float4*)(fp + 4);
    float4 o0 = make_float4(fmaxf(s[0] + c0.x, 0.f), fmaxf(s[1] + c0.y, 0.f),
                            fmaxf(s[2] + c0.z, 0.f), fmaxf(s[3] + c0.w, 0.f));
    float4 o1 = make_float4(fmaxf(s[4] + c1.x, 0.f), fmaxf(s[5] + c1.y, 0.f),
                            fmaxf(s[6] + c1.z, 0.f), fmaxf(s[7] + c1.w, 0.f));
    *(float4*)fp = o0;
    *(float4*)(fp + 4) = o1;
  }
}

// ---------------- readout ----------------
__global__ __launch_bounds__(256) void k_gather(const int* __restrict__ srcn,
                                                const int* __restrict__ tgtn,
                                                const float* __restrict__ feats,
                                                float* __restrict__ out) {
  int id = blockIdx.x * 256 + threadIdx.x;
  if (id >= 2 * NSRC * 256) return;
  int half = id / (NSRC * 256);
  int rem = id % (NSRC * 256);
  int s = rem >> 8, c = rem & 255;
  int n = half ? tgtn[s] : srcn[s];
  int base = GG * 256 + half * NSRC * 256;
  out[base + s * 256 + c] = feats[n * 256 + c];
}

__global__ __launch_bounds__(256) void k_zero(float* __restrict__ p, int n) {
  int id = blockIdx.x * 256 + threadIdx.x;
  if (id < n) p[id] = 0.0f;
}

__global__ __launch_bounds__(256) void k_graphsum(const int* __restrict__ gid,
                                                  const float* __restrict__ feats,
                                                  float* __restrict__ gsum,
                                                  float* __restrict__ gcnt) {
  const int g = blockIdx.x / GCH, ch = blockIdx.x % GCH;
  __shared__ int sb[2];
  if (threadIdx.x == 0) {
    int lo = 0, hi = NN;
    while (lo < hi) { int m = (lo + hi) >> 1; if (gid[m] < g) lo = m + 1; else hi = m; }
    sb[0] = lo;
    lo = 0; hi = NN;
    while (lo < hi) { int m = (lo + hi) >> 1; if (gid[m] < g + 1) lo = m + 1; else hi = m; }
    sb[1] = lo;
  }
  __syncthreads();
  const int lo = sb[0], hi = sb[1];
  if (ch == 0 && threadIdx.x == 0) gcnt[g] = (float)(hi - lo);
  const int cnt = hi - lo;
  const int per = (cnt + GCH - 1) / GCH;
  const int nlo = lo + ch * per, nhi = min(nlo + per, hi);
  float s = 0.0f;
  const int c = threadIdx.x;
  for (int n = nlo; n < nhi; ++n) s += feats[n * 256 + c];
  atomicAdd(&gsum[g * 256 + c], s);
}

__global__ __launch_bounds__(256) void k_graphdiv(const float* __restrict__ gsum,
                                                  const float* __restrict__ gcnt,
                                                  float* __restrict__ out) {
  int id = blockIdx.x * 256 + threadIdx.x;
  if (id >= GG * 256) return;
  out[id] = gsum[id] / gcnt[id >> 8];
}

extern "C" void kernel_launch(void* const* d_in, const int* in_sizes, int n_in,
                              void* d_out, int out_size, void* d_ws, size_t ws_size,
                              hipStream_t stream) {
  const float* node_feat  = (const float*)d_in[0];
  const int*   edge       = (const int*)d_in[1];
  const int*   rel        = (const int*)d_in[2];
  const float* re         = (const float*)d_in[3];
  const float* tr         = (const float*)d_in[4];
  const int*   srcn       = (const int*)d_in[5];
  const int*   tgtn       = (const int*)d_in[6];
  const int*   gid        = (const int*)d_in[7];
  const float* weights    = (const float*)d_in[8];
  const float* w_comps    = (const float*)d_in[9];
  const float* self_loops = (const float*)d_in[10];
  const float* A_w        = (const float*)d_in[11];
  const float* A_b        = (const float*)d_in[12];
  const float* B_w        = (const float*)d_in[13];
  const float* B_b        = (const float*)d_in[14];
  float* out = (float*)d_out;

  float* ws    = (float*)d_ws;
  float* feats = ws;                            // N*256 f32
  float* gsum  = feats + (size_t)NN * 256;      // GG*256
  float* gcnt  = gsum + GG * 256;               // 64
  float* aatt  = gcnt + 64;                     // E
  float* acf   = aatt + EE;                     // E*4
  _Float16* xw16  = (_Float16*)(acf + (size_t)EE * 4);  // N*512 fp16
  _Float16* pst16 = xw16 + (size_t)NN * 512;            // N*256 fp16
  unsigned short* Xhi  = (unsigned short*)(pst16 + (size_t)NN * 256);  // NP*128
  unsigned short* Xlo  = Xhi + (size_t)NP * 128;
  unsigned short* BThi = Xlo + (size_t)NP * 128;        // 896*128
  unsigned short* BTlo = BThi + 896 * 128;
  int* deg    = (int*)(BTlo + 896 * 128);       // N
  int* rowptr = deg + NN;                       // N+1
  int* cursor = rowptr + NN + 1;                // N
  int* eidx   = cursor + NN;                    // E
  int* srcs   = eidx + EE;                      // E
  // total ws ~171 MB

  const int* e_src = edge;
  const int* e_tgt = edge + EE;

  // CSR by tgt (layer-invariant)
  k_zero_i<<<(NN + 255) / 256, 256, 0, stream>>>(deg, NN);
  k_hist<<<(EE + 255) / 256, 256, 0, stream>>>(e_tgt, deg);
  k_scan<<<1, 1024, 0, stream>>>(deg, rowptr, cursor);
  k_fill<<<(EE + 255) / 256, 256, 0, stream>>>(e_tgt, cursor, eidx);

  for (int l = 0; l < LL; ++l) {
    const float* X = (l == 0) ? node_feat : feats;  // layer1 input = feats[:, 0:128]
    int xs = (l == 0) ? 128 : 256;
    k_bigwT<<<(128 * 896 + 255) / 256, 256, 0, stream>>>(weights, A_w, self_loops,
                                                         BThi, BTlo, l);
    k_splitX<<<(NP * 128 + 255) / 256, 256, 0, stream>>>(X, xs, Xhi, Xlo);
    dim3 g1(NP / 64, 7);
    k_mgemm<<<g1, 256, 0, stream>>>(Xhi, Xlo, BThi, BTlo, xw16, pst16, feats + l * 128);
    k_attn<<<EE / 64, 256, 0, stream>>>(e_src, e_tgt, re, tr, A_w, A_b, B_w, B_b,
                                        pst16, aatt, l);
    k_prep<<<(EE + 255) / 256, 256, 0, stream>>>(eidx, e_src, rel, aatt, w_comps,
                                                 srcs, acf, l);
    k_reduce<<<(NN + 3) / 4, 256, 0, stream>>>(rowptr, srcs, acf, xw16, feats, l);
  }
  k_gather<<<(2 * NSRC * 256 + 255) / 256, 256, 0, stream>>>(srcn, tgtn, feats, out);
  k_zero<<<(GG * 256 + 64 + 255) / 256, 256, 0, stream>>>(gsum, GG * 256 + 64);
  k_graphsum<<<GG * GCH, 256, 0, stream>>>(gid, feats, gsum, gcnt);
  k_graphdiv<<<GG, 256, 0, stream>>>(gsum, gcnt, out);
}

// Round 5
// 1064.232 us; speedup vs baseline: 3.5023x; 1.2423x over previous
//
#include <hip/hip_runtime.h>

// RGCN: N=50000, E=600000, D=128, R=200, NB=4, ARD=32, L=2, G=50, NS=2000
// R4: k_mgemm rebuilt as LDS-tiled MFMA GEMM (128m x 128n block, B staged in LDS
//     with bank-safe stride, LDS-transpose epilogue -> coalesced half8/float4 row
//     stores; kills the 2B-scattered-store RMW traffic and 4x the B reuse).
//     k_prep folded away: k_fill emits CSR-order srcs + inverse perm epos;
//     k_attn scatters a*cf4 directly into acf[epos[e]].
//   per layer l:
//     k_bigwT  : BigW^T split -> BThi/BTlo [896][128] bf16
//     k_splitX : X -> Xhi/Xlo bf16x2 (NP=50048 padded)
//     k_mgemm  : 3-pass bf16x2 MFMA -> xw16 (Nx512 fp16), pst16 (Nx256 fp16),
//                curr -> feats[:, l*128:+128] fp32
//     k_attn   : per-64-edge q-GEMM (VALU) + MLP -> acf (CSR order)
//     k_reduce : wave-per-tgt CSR reduction over fp16 xw, fp32 accum
// All accumulation fp32. ws ~171 MB.

#define NN 50000
#define NP 50048   // 391 * 128
#define EE 600000
#define DD 128
#define RR 200
#define NBASIS 4
#define LL 2
#define GG 50
#define NSRC 2000
#define GCH 8

typedef __attribute__((ext_vector_type(8))) short short8v;
typedef __attribute__((ext_vector_type(4))) float float4v;
typedef __attribute__((ext_vector_type(8))) _Float16 half8v;
typedef __attribute__((ext_vector_type(4))) _Float16 half4v;

__device__ __forceinline__ void f4a(const float4 v, float* a) {
  a[0] = v.x; a[1] = v.y; a[2] = v.z; a[3] = v.w;
}

__device__ __forceinline__ unsigned short f2bf(float v) {  // RNE bf16
  unsigned u = __float_as_uint(v);
  unsigned r = u + 0x7FFFu + ((u >> 16) & 1u);
  return (unsigned short)(r >> 16);
}
__device__ __forceinline__ float bf2f(unsigned short h) {
  return __uint_as_float(((unsigned)h) << 16);
}

// ---------------- BigW^T assembly + bf16x2 split: BT*[c*128 + i] ----------------
__global__ __launch_bounds__(256) void k_bigwT(const float* __restrict__ weights,
                                               const float* __restrict__ A_w,
                                               const float* __restrict__ self_loops,
                                               unsigned short* __restrict__ BThi,
                                               unsigned short* __restrict__ BTlo, int l) {
  int id = blockIdx.x * 256 + threadIdx.x;
  if (id >= 128 * 896) return;
  int i = id / 896, c = id % 896;  // i = K index, c = output col
  float v;
  if (c < 512) {            // xw: col b*128+o = weights[l][b][i][o]
    int b = c >> 7, o = c & 127;
    v = weights[((l * NBASIS + b) * DD + i) * DD + o];
  } else if (c < 640) {     // psrc
    int j = c - 512;
    v = A_w[(l * DD + j) * 320 + i];
  } else if (c < 768) {     // ptgt
    int j = c - 640;
    v = A_w[(l * DD + j) * 320 + 128 + i];
  } else {                  // curr
    int o = c - 768;
    v = self_loops[(l * DD + i) * DD + o];
  }
  unsigned short hi = f2bf(v);
  unsigned short lo = f2bf(v - bf2f(hi));
  BThi[c * 128 + i] = hi;
  BTlo[c * 128 + i] = lo;
}

// ---------------- X bf16x2 split (padded to NP rows) ----------------
__global__ __launch_bounds__(256) void k_splitX(const float* __restrict__ X, int xs,
                                                unsigned short* __restrict__ Xhi,
                                                unsigned short* __restrict__ Xlo) {
  int id = blockIdx.x * 256 + threadIdx.x;
  if (id >= NP * 128) return;
  int n = id >> 7, k = id & 127;
  float v = (n < NN) ? X[(size_t)n * xs + k] : 0.0f;
  unsigned short hi = f2bf(v);
  unsigned short lo = f2bf(v - bf2f(hi));
  Xhi[id] = hi;
  Xlo[id] = lo;
}

// ---------------- MFMA node GEMM: block 128m x 128n, wave 32m x 128n ----------------
// LDS: K-loop stages B (hi+lo) at stride 56 halves (2-way banks, 16B aligned);
// epilogue reuses LDS for C transpose -> coalesced row stores.
__global__ __launch_bounds__(256) void k_mgemm(const unsigned short* __restrict__ Xhi,
                                               const unsigned short* __restrict__ Xlo,
                                               const unsigned short* __restrict__ BThi,
                                               const unsigned short* __restrict__ BTlo,
                                               _Float16* __restrict__ xw16,
                                               _Float16* __restrict__ pst16,
                                               float* __restrict__ currdst) {
  __shared__ __align__(16) char smem[34816];
  unsigned short* sBhi = (unsigned short*)smem;        // [128][56] halves
  unsigned short* sBlo = sBhi + 128 * 56;
  _Float16* sC = (_Float16*)smem;                      // [128][136] halves (34816 B)
  float* sCf = (float*)smem;                           // [64][132] floats (33792 B)

  const int t = threadIdx.x;
  const int wv = t >> 6, lane = t & 63;
  const int lm = lane & 15, qd = lane >> 4;
  const int m0 = blockIdx.x * 128;
  const int cb = blockIdx.y;           // 0..6
  const int n0 = cb * 128;
  const int mw = m0 + wv * 32;         // wave's 32-row strip

  float4v acc[2][8];
#pragma unroll
  for (int mi = 0; mi < 2; ++mi)
#pragma unroll
    for (int nt = 0; nt < 8; ++nt) acc[mi][nt] = (float4v)(0.0f);

  const int sn = (t >> 2);             // staging row 0..63 (+64 on rep 1)
  const int skq = (t & 3) * 8;         // staging k-offset (halves)

  for (int kc = 0; kc < 128; kc += 32) {
    // stage B tile (128n x 32k, hi+lo) -> LDS
    short8v vh0 = *(const short8v*)(BThi + (size_t)(n0 + sn) * 128 + kc + skq);
    short8v vl0 = *(const short8v*)(BTlo + (size_t)(n0 + sn) * 128 + kc + skq);
    short8v vh1 = *(const short8v*)(BThi + (size_t)(n0 + 64 + sn) * 128 + kc + skq);
    short8v vl1 = *(const short8v*)(BTlo + (size_t)(n0 + 64 + sn) * 128 + kc + skq);
    if (kc) __syncthreads();           // prev tile's reads complete
    *(short8v*)&sBhi[sn * 56 + skq] = vh0;
    *(short8v*)&sBlo[sn * 56 + skq] = vl0;
    *(short8v*)&sBhi[(64 + sn) * 56 + skq] = vh1;
    *(short8v*)&sBlo[(64 + sn) * 56 + skq] = vl1;
    __syncthreads();
    // A fragments direct from global (L3-resident)
    short8v ah[2], al[2];
#pragma unroll
    for (int mi = 0; mi < 2; ++mi) {
      ah[mi] = *(const short8v*)(Xhi + (size_t)(mw + mi * 16 + lm) * 128 + kc + qd * 8);
      al[mi] = *(const short8v*)(Xlo + (size_t)(mw + mi * 16 + lm) * 128 + kc + qd * 8);
    }
#pragma unroll
    for (int nt = 0; nt < 8; ++nt) {
      short8v bh = *(const short8v*)&sBhi[(nt * 16 + lm) * 56 + qd * 8];
      short8v bl = *(const short8v*)&sBlo[(nt * 16 + lm) * 56 + qd * 8];
#pragma unroll
      for (int mi = 0; mi < 2; ++mi) {
        acc[mi][nt] = __builtin_amdgcn_mfma_f32_16x16x32_bf16(ah[mi], bh, acc[mi][nt], 0, 0, 0);
        acc[mi][nt] = __builtin_amdgcn_mfma_f32_16x16x32_bf16(ah[mi], bl, acc[mi][nt], 0, 0, 0);
        acc[mi][nt] = __builtin_amdgcn_mfma_f32_16x16x32_bf16(al[mi], bh, acc[mi][nt], 0, 0, 0);
      }
    }
  }

  // epilogue: C/D layout col = lane&15, row = qd*4 + reg  [m89/m91]
  if (cb < 6) {                        // fp16 tables, LDS transpose -> half8 row stores
    _Float16* dst16; int stride, off;
    if (cb < 4) { dst16 = xw16;  stride = 512; off = cb * 128; }
    else        { dst16 = pst16; stride = 256; off = (cb - 4) * 128; }
    __syncthreads();
#pragma unroll
    for (int mi = 0; mi < 2; ++mi)
#pragma unroll
      for (int nt = 0; nt < 8; ++nt)
#pragma unroll
        for (int r = 0; r < 4; ++r)
          sC[(wv * 32 + mi * 16 + qd * 4 + r) * 136 + nt * 16 + lm] =
              (_Float16)acc[mi][nt][r];
    __syncthreads();
#pragma unroll
    for (int rep = 0; rep < 8; ++rep) {
      int idx = rep * 256 + t;
      int row = idx >> 4, li = idx & 15;
      int m = m0 + row;
      if (m < NN)
        *(half8v*)&dst16[(size_t)m * stride + off + li * 8] =
            *(const half8v*)&sC[row * 136 + li * 8];
    }
  } else {                             // curr -> fp32 feats, two 64-row passes
#pragma unroll
    for (int pass = 0; pass < 2; ++pass) {
      __syncthreads();
      if ((wv >> 1) == pass) {
        int rbase = (wv & 1) * 32;
#pragma unroll
        for (int mi = 0; mi < 2; ++mi)
#pragma unroll
          for (int nt = 0; nt < 8; ++nt)
#pragma unroll
            for (int r = 0; r < 4; ++r)
              sCf[(rbase + mi * 16 + qd * 4 + r) * 132 + nt * 16 + lm] = acc[mi][nt][r];
      }
      __syncthreads();
#pragma unroll
      for (int rep = 0; rep < 8; ++rep) {
        int idx = rep * 256 + t;
        int lr = idx >> 5, li = idx & 31;
        int m = m0 + pass * 64 + lr;
        if (m < NN)
          *(float4*)&currdst[(size_t)m * 256 + li * 4] =
              *(const float4*)&sCf[lr * 132 + li * 4];
      }
    }
  }
}

// ---------------- Attention: 64 edges/block, q-GEMM + MLP -> acf[epos[e]] ----------------
__global__ __launch_bounds__(256) void k_attn(
    const int* __restrict__ e_src, const int* __restrict__ e_tgt,
    const int* __restrict__ rel, const int* __restrict__ epos,
    const float* __restrict__ re, const float* __restrict__ tr,
    const float* __restrict__ A_w, const float* __restrict__ A_b,
    const float* __restrict__ B_w, const float* __restrict__ B_b,
    const float* __restrict__ w_comps,
    const _Float16* __restrict__ pst16, float* __restrict__ acf, int l) {
  __shared__ __align__(16) float sA[64 * 132];   // Acat[k][j] = A_w[l][j][256+k]
  __shared__ __align__(16) float sEt[64 * 68];   // ecat[k][e]
  __shared__ float sBw[128], sAb[128];
  __shared__ int sSrc[64], sTgt[64];
  const int t = threadIdx.x;
  const int tx = t & 15, ty = t >> 4;
  const int e0 = blockIdx.x * 64;
#pragma unroll
  for (int r = 0; r < 32; ++r) {
    int flat = r * 256 + t;
    int j = flat >> 6, k = flat & 63;
    sA[k * 132 + j] = A_w[(l * DD + j) * 320 + 256 + k];
  }
#pragma unroll
  for (int r = 0; r < 16; ++r) {
    int flat = r * 256 + t;
    int e = flat >> 6, k = flat & 63;
    int eg = e0 + e;
    sEt[k * 68 + e] = (k < 32) ? re[eg * 32 + k] : tr[eg * 32 + (k - 32)];
  }
  if (t < 64) { sSrc[t] = e_src[e0 + t]; sTgt[t] = e_tgt[e0 + t]; }
  if (t < 128) { sBw[t] = B_w[l * DD + t]; sAb[t] = A_b[l * DD + t]; }
  __syncthreads();
  const float Bb = B_b[l];

  float q0[4][4] = {{0}}, q1[4][4] = {{0}};
#pragma unroll 8
  for (int k = 0; k < 64; ++k) {
    float ea[4], aa[4], ab[4];
    f4a(*(const float4*)&sEt[k * 68 + ty * 4], ea);
    f4a(*(const float4*)&sA[k * 132 + tx * 4], aa);
    f4a(*(const float4*)&sA[k * 132 + 64 + tx * 4], ab);
#pragma unroll
    for (int i2 = 0; i2 < 4; ++i2)
#pragma unroll
      for (int j2 = 0; j2 < 4; ++j2) {
        q0[i2][j2] += ea[i2] * aa[j2];
        q1[i2][j2] += ea[i2] * ab[j2];
      }
  }

#pragma unroll
  for (int i2 = 0; i2 < 4; ++i2) {
    const int el = ty * 4 + i2;
    const int src = sSrc[el], tgt = sTgt[el];
    half4v hp0 = *(const half4v*)&pst16[(size_t)src * 256 + tx * 4];
    half4v hp1 = *(const half4v*)&pst16[(size_t)src * 256 + 64 + tx * 4];
    half4v ht0 = *(const half4v*)&pst16[(size_t)tgt * 256 + 128 + tx * 4];
    half4v ht1 = *(const half4v*)&pst16[(size_t)tgt * 256 + 192 + tx * 4];
    float part = 0.0f;
#pragma unroll
    for (int j2 = 0; j2 < 4; ++j2) {
      float h0 = fmaxf((float)hp0[j2] + (float)ht0[j2] + q0[i2][j2] + sAb[tx * 4 + j2], 0.0f);
      float h1 = fmaxf((float)hp1[j2] + (float)ht1[j2] + q1[i2][j2] + sAb[64 + tx * 4 + j2], 0.0f);
      part += h0 * sBw[tx * 4 + j2] + h1 * sBw[64 + tx * 4 + j2];
    }
#pragma unroll
    for (int m = 1; m < 16; m <<= 1) part += __shfl_xor(part, m, 64);
    if (tx == 0) {
      const int e = e0 + el;
      const float a = 1.0f / (1.0f + expf(-(part + Bb)));
      const float4 cf = *(const float4*)&w_comps[(l * RR + rel[e]) * 4];
      const int p = epos[e];
      *(float4*)&acf[(size_t)p * 4] = make_float4(a * cf.x, a * cf.y, a * cf.z, a * cf.w);
    }
  }
}

// ---------------- CSR build ----------------
__global__ __launch_bounds__(256) void k_zero_i(int* __restrict__ p, int n) {
  int id = blockIdx.x * 256 + threadIdx.x;
  if (id < n) p[id] = 0;
}
__global__ __launch_bounds__(256) void k_hist(const int* __restrict__ e_tgt,
                                              int* __restrict__ deg) {
  int e = blockIdx.x * 256 + threadIdx.x;
  if (e < EE) atomicAdd(&deg[e_tgt[e]], 1);
}
__global__ __launch_bounds__(1024) void k_scan(const int* __restrict__ deg,
                                               int* __restrict__ rowptr,
                                               int* __restrict__ cursor) {
  __shared__ int part[1024];
  const int t = threadIdx.x;
  const int chunk = (NN + 1023) / 1024;  // 49
  int lo = t * chunk, hi = min(lo + chunk, NN);
  int s = 0;
  for (int i = lo; i < hi; ++i) s += deg[i];
  part[t] = s;
  __syncthreads();
  for (int off = 1; off < 1024; off <<= 1) {
    int v = (t >= off) ? part[t - off] : 0;
    __syncthreads();
    part[t] += v;
    __syncthreads();
  }
  int run = (t == 0) ? 0 : part[t - 1];
  for (int i = lo; i < hi; ++i) {
    int d = deg[i];
    rowptr[i] = run; cursor[i] = run;
    run += d;
  }
  if (t == 0) rowptr[NN] = EE;
}
// fill: eidx + CSR-order srcs + inverse perm epos (all layer-invariant)
__global__ __launch_bounds__(256) void k_fill(const int* __restrict__ e_tgt,
                                              const int* __restrict__ e_src,
                                              int* __restrict__ cursor,
                                              int* __restrict__ srcs,
                                              int* __restrict__ epos) {
  int e = blockIdx.x * 256 + threadIdx.x;
  if (e < EE) {
    int p = atomicAdd(&cursor[e_tgt[e]], 1);
    srcs[p] = e_src[e];
    epos[e] = p;
  }
}

// ---------------- CSR segmented reduction: one wave per tgt node ----------------
__global__ __launch_bounds__(256) void k_reduce(
    const int* __restrict__ rowptr, const int* __restrict__ srcs,
    const float* __restrict__ acf, const _Float16* __restrict__ xw16,
    float* __restrict__ feats, int l) {
  const int t = threadIdx.x;
  const int wave = t >> 6, lane = t & 63;
  const int n = blockIdx.x * 4 + wave;
  if (n >= NN) return;
  const int b = lane >> 4, li = lane & 15;
  float s[8] = {0, 0, 0, 0, 0, 0, 0, 0};
  const int lo = rowptr[n], hi = rowptr[n + 1];
  int snext = 0; float cnext = 0.0f;
  if (lo < hi) { snext = srcs[lo]; cnext = acf[lo * 4 + b]; }
  for (int i = lo; i < hi; ++i) {
    const int src = snext; const float cb_ = cnext;
    if (i + 1 < hi) { snext = srcs[i + 1]; cnext = acf[(i + 1) * 4 + b]; }
    half8v x = *(const half8v*)&xw16[(size_t)src * 512 + b * 128 + li * 8];
#pragma unroll
    for (int j = 0; j < 8; ++j) s[j] += cb_ * (float)x[j];
  }
#pragma unroll
  for (int j = 0; j < 8; ++j) {
    s[j] += __shfl_xor(s[j], 16, 64);
    s[j] += __shfl_xor(s[j], 32, 64);
  }
  if (lane < 16) {
    float* fp = &feats[(size_t)n * 256 + l * 128 + lane * 8];
    float4 c0 = *(const float4*)fp;
    float4 c1 = *(const float4*)(fp + 4);
    float4 o0 = make_float4(fmaxf(s[0] + c0.x, 0.f), fmaxf(s[1] + c0.y, 0.f),
                            fmaxf(s[2] + c0.z, 0.f), fmaxf(s[3] + c0.w, 0.f));
    float4 o1 = make_float4(fmaxf(s[4] + c1.x, 0.f), fmaxf(s[5] + c1.y, 0.f),
                            fmaxf(s[6] + c1.z, 0.f), fmaxf(s[7] + c1.w, 0.f));
    *(float4*)fp = o0;
    *(float4*)(fp + 4) = o1;
  }
}

// ---------------- readout ----------------
__global__ __launch_bounds__(256) void k_gather(const int* __restrict__ srcn,
                                                const int* __restrict__ tgtn,
                                                const float* __restrict__ feats,
                                                float* __restrict__ out) {
  int id = blockIdx.x * 256 + threadIdx.x;
  if (id >= 2 * NSRC * 256) return;
  int half = id / (NSRC * 256);
  int rem = id % (NSRC * 256);
  int s = rem >> 8, c = rem & 255;
  int n = half ? tgtn[s] : srcn[s];
  int base = GG * 256 + half * NSRC * 256;
  out[base + s * 256 + c] = feats[n * 256 + c];
}

__global__ __launch_bounds__(256) void k_zero(float* __restrict__ p, int n) {
  int id = blockIdx.x * 256 + threadIdx.x;
  if (id < n) p[id] = 0.0f;
}

__global__ __launch_bounds__(256) void k_graphsum(const int* __restrict__ gid,
                                                  const float* __restrict__ feats,
                                                  float* __restrict__ gsum,
                                                  float* __restrict__ gcnt) {
  const int g = blockIdx.x / GCH, ch = blockIdx.x % GCH;
  __shared__ int sb[2];
  if (threadIdx.x == 0) {
    int lo = 0, hi = NN;
    while (lo < hi) { int m = (lo + hi) >> 1; if (gid[m] < g) lo = m + 1; else hi = m; }
    sb[0] = lo;
    lo = 0; hi = NN;
    while (lo < hi) { int m = (lo + hi) >> 1; if (gid[m] < g + 1) lo = m + 1; else hi = m; }
    sb[1] = lo;
  }
  __syncthreads();
  const int lo = sb[0], hi = sb[1];
  if (ch == 0 && threadIdx.x == 0) gcnt[g] = (float)(hi - lo);
  const int cnt = hi - lo;
  const int per = (cnt + GCH - 1) / GCH;
  const int nlo = lo + ch * per, nhi = min(nlo + per, hi);
  float s = 0.0f;
  const int c = threadIdx.x;
  for (int n = nlo; n < nhi; ++n) s += feats[n * 256 + c];
  atomicAdd(&gsum[g * 256 + c], s);
}

__global__ __launch_bounds__(256) void k_graphdiv(const float* __restrict__ gsum,
                                                  const float* __restrict__ gcnt,
                                                  float* __restrict__ out) {
  int id = blockIdx.x * 256 + threadIdx.x;
  if (id >= GG * 256) return;
  out[id] = gsum[id] / gcnt[id >> 8];
}

extern "C" void kernel_launch(void* const* d_in, const int* in_sizes, int n_in,
                              void* d_out, int out_size, void* d_ws, size_t ws_size,
                              hipStream_t stream) {
  const float* node_feat  = (const float*)d_in[0];
  const int*   edge       = (const int*)d_in[1];
  const int*   rel        = (const int*)d_in[2];
  const float* re         = (const float*)d_in[3];
  const float* tr         = (const float*)d_in[4];
  const int*   srcn       = (const int*)d_in[5];
  const int*   tgtn       = (const int*)d_in[6];
  const int*   gid        = (const int*)d_in[7];
  const float* weights    = (const float*)d_in[8];
  const float* w_comps    = (const float*)d_in[9];
  const float* self_loops = (const float*)d_in[10];
  const float* A_w        = (const float*)d_in[11];
  const float* A_b        = (const float*)d_in[12];
  const float* B_w        = (const float*)d_in[13];
  const float* B_b        = (const float*)d_in[14];
  float* out = (float*)d_out;

  float* ws    = (float*)d_ws;
  float* feats = ws;                            // N*256 f32
  float* gsum  = feats + (size_t)NN * 256;      // GG*256
  float* gcnt  = gsum + GG * 256;               // 64
  float* acf   = gcnt + 64;                     // E*4
  _Float16* xw16  = (_Float16*)(acf + (size_t)EE * 4);  // N*512 fp16
  _Float16* pst16 = xw16 + (size_t)NN * 512;            // N*256 fp16
  unsigned short* Xhi  = (unsigned short*)(pst16 + (size_t)NN * 256);  // NP*128
  unsigned short* Xlo  = Xhi + (size_t)NP * 128;
  unsigned short* BThi = Xlo + (size_t)NP * 128;        // 896*128
  unsigned short* BTlo = BThi + 896 * 128;
  int* deg    = (int*)(BTlo + 896 * 128);       // N
  int* rowptr = deg + NN;                       // N+1
  int* cursor = rowptr + NN + 1;                // N
  int* srcs   = cursor + NN;                    // E
  int* epos   = srcs + EE;                      // E
  // total ws ~169 MB

  const int* e_src = edge;
  const int* e_tgt = edge + EE;

  // CSR by tgt (layer-invariant)
  k_zero_i<<<(NN + 255) / 256, 256, 0, stream>>>(deg, NN);
  k_hist<<<(EE + 255) / 256, 256, 0, stream>>>(e_tgt, deg);
  k_scan<<<1, 1024, 0, stream>>>(deg, rowptr, cursor);
  k_fill<<<(EE + 255) / 256, 256, 0, stream>>>(e_tgt, e_src, cursor, srcs, epos);

  for (int l = 0; l < LL; ++l) {
    const float* X = (l == 0) ? node_feat : feats;  // layer1 input = feats[:, 0:128]
    int xs = (l == 0) ? 128 : 256;
    k_bigwT<<<(128 * 896 + 255) / 256, 256, 0, stream>>>(weights, A_w, self_loops,
                                                         BThi, BTlo, l);
    k_splitX<<<(NP * 128 + 255) / 256, 256, 0, stream>>>(X, xs, Xhi, Xlo);
    dim3 g1(NP / 128, 7);
    k_mgemm<<<g1, 256, 0, stream>>>(Xhi, Xlo, BThi, BTlo, xw16, pst16, feats + l * 128);
    k_attn<<<EE / 64, 256, 0, stream>>>(e_src, e_tgt, rel, epos, re, tr, A_w, A_b,
                                        B_w, B_b, w_comps, pst16, acf, l);
    k_reduce<<<(NN + 3) / 4, 256, 0, stream>>>(rowptr, srcs, acf, xw16, feats, l);
  }
  k_gather<<<(2 * NSRC * 256 + 255) / 256, 256, 0, stream>>>(srcn, tgtn, feats, out);
  k_zero<<<(GG * 256 + 64 + 255) / 256, 256, 0, stream>>>(gsum, GG * 256 + 64);
  k_graphsum<<<GG * GCH, 256, 0, stream>>>(gid, feats, gsum, gcnt);
  k_graphdiv<<<GG, 256, 0, stream>>>(gsum, gcnt, out);
}